// Round 5
// baseline (956.579 us; speedup 1.0000x reference)
//
#include <hip/hip_runtime.h>
#include <hip/hip_bf16.h>
#include <math.h>

__device__ inline unsigned f2bf(float f) {
    union { __hip_bfloat16 h; unsigned short u; } cv;
    cv.h = __float2bfloat16(f);
    return (unsigned)cv.u;
}

// ---------------- CSR construction ----------------

__global__ void k_hist(const int* __restrict__ dst, int* __restrict__ counts, int E) {
    int e = blockIdx.x * blockDim.x + threadIdx.x;
    if (e < E) atomicAdd(&counts[dst[e]], 1);
}

__global__ void k_scan1(const int* __restrict__ counts, int* __restrict__ row_ptr,
                        int* __restrict__ csum, int n) {
    __shared__ int buf[1024];
    int tid = threadIdx.x;
    int base = blockIdx.x * 1024;
    int v = (base + tid < n) ? counts[base + tid] : 0;
    buf[tid] = v;
    __syncthreads();
    int inc = v;
    for (int off = 1; off < 1024; off <<= 1) {
        int add = (tid >= off) ? buf[tid - off] : 0;
        __syncthreads();
        inc += add;
        buf[tid] = inc;
        __syncthreads();
    }
    if (base + tid < n) row_ptr[base + tid] = inc - v;
    if (tid == 1023) csum[blockIdx.x] = inc;
}

__global__ void k_scan2(int* __restrict__ csum, int nc, int* __restrict__ total) {
    if (threadIdx.x == 0) {
        int run = 0;
        for (int i = 0; i < nc; ++i) { int c = csum[i]; csum[i] = run; run += c; }
        *total = run;
    }
}

__global__ void k_scan3(int* __restrict__ row_ptr, const int* __restrict__ csum,
                        const int* __restrict__ total, int n) {
    int i = blockIdx.x * blockDim.x + threadIdx.x;
    if (i < n) row_ptr[i] += csum[i >> 10];
    if (i == 0) row_ptr[n] = *total;
}

__global__ void k_scatter(const int* __restrict__ src, const int* __restrict__ dst,
                          const int* __restrict__ row_ptr, int* __restrict__ fill,
                          int* __restrict__ src_perm, int* __restrict__ eid_perm, int E) {
    int e = blockIdx.x * blockDim.x + threadIdx.x;
    if (e >= E) return;
    int d = dst[e];
    int pos = row_ptr[d] + atomicAdd(&fill[d], 1);
    src_perm[pos] = src[e];
    eid_perm[pos] = e;
}

__global__ void k_gptr(const int* __restrict__ batch, int* __restrict__ gptr, int n, int G) {
    int i = blockIdx.x * blockDim.x + threadIdx.x;
    if (i > n) return;
    if (i == 0) {
        int b0 = batch[0];
        for (int g = 0; g <= b0; ++g) gptr[g] = 0;
    } else if (i == n) {
        int bl = batch[n - 1];
        for (int g = bl + 1; g <= G; ++g) gptr[g] = n;
    } else {
        int b = batch[i], pb = batch[i - 1];
        for (int g = pb + 1; g <= b; ++g) gptr[g] = i;
    }
}

// ---------------- weight transpose (tiny) ----------------

__global__ void k_wt(const float* __restrict__ W1, const float* __restrict__ W2,
                     float* __restrict__ W1t, float* __restrict__ W2t) {
    int tid = blockIdx.x * blockDim.x + threadIdx.x;
    if (tid < 1024) {
        int j = tid / 16, k = tid % 16;
        W1t[j * 16 + k] = W1[k * 64 + j];
    }
    if (tid < 4096) {
        int j = tid / 64, k = tid % 64;
        W2t[j * 64 + k] = W2[k * 64 + j];
    }
}

// ---------------- Atom encoder: [M,32] -> relu -> [M,64] -> relu ----------------

#define TM 128
__global__ __launch_bounds__(256) void k_atom(const float* __restrict__ x,
        const float* __restrict__ W1, const float* __restrict__ b1,
        const float* __restrict__ W2, const float* __restrict__ b2,
        float* __restrict__ out, int M) {
    __shared__ float sU[TM * 65];
    __shared__ float sW1[32 * 64];
    __shared__ float sW2[64 * 64];
    __shared__ float sB1[64], sB2[64];
#define A_IN(r, c) sU[(r) * 33 + (c)]
#define A_T1(r, c) sU[(r) * 65 + (c)]
    int tid = threadIdx.x;
    int base = blockIdx.x * TM;
    for (int i = tid; i < 32 * 64 / 4; i += 256) ((float4*)sW1)[i] = ((const float4*)W1)[i];
    for (int i = tid; i < 64 * 64 / 4; i += 256) ((float4*)sW2)[i] = ((const float4*)W2)[i];
    if (tid < 64) { sB1[tid] = b1[tid]; sB2[tid] = b2[tid]; }
    for (int i = tid; i < TM * 32 / 4; i += 256) {
        int r = i / 8, c4 = i % 8;
        int row = base + r;
        float4 v = (row < M) ? ((const float4*)(x + (long)row * 32))[c4] : make_float4(0, 0, 0, 0);
        A_IN(r, c4 * 4 + 0) = v.x; A_IN(r, c4 * 4 + 1) = v.y;
        A_IN(r, c4 * 4 + 2) = v.z; A_IN(r, c4 * 4 + 3) = v.w;
    }
    __syncthreads();
    int r0 = (tid / 16) * 8;
    int c0 = (tid % 16) * 4;
    float acc[8][4];
#pragma unroll
    for (int i = 0; i < 8; i++)
#pragma unroll
        for (int j = 0; j < 4; j++) acc[i][j] = sB1[c0 + j];
    for (int k = 0; k < 32; k++) {
        float a[8], b[4];
#pragma unroll
        for (int i = 0; i < 8; i++) a[i] = A_IN(r0 + i, k);
#pragma unroll
        for (int j = 0; j < 4; j++) b[j] = sW1[k * 64 + c0 + j];
#pragma unroll
        for (int i = 0; i < 8; i++)
#pragma unroll
            for (int j = 0; j < 4; j++) acc[i][j] += a[i] * b[j];
    }
    __syncthreads();
#pragma unroll
    for (int i = 0; i < 8; i++)
#pragma unroll
        for (int j = 0; j < 4; j++) A_T1(r0 + i, c0 + j) = fmaxf(acc[i][j], 0.f);
    __syncthreads();
#pragma unroll
    for (int i = 0; i < 8; i++)
#pragma unroll
        for (int j = 0; j < 4; j++) acc[i][j] = sB2[c0 + j];
    for (int k = 0; k < 64; k++) {
        float a[8], b[4];
#pragma unroll
        for (int i = 0; i < 8; i++) a[i] = A_T1(r0 + i, k);
#pragma unroll
        for (int j = 0; j < 4; j++) b[j] = sW2[k * 64 + c0 + j];
#pragma unroll
        for (int i = 0; i < 8; i++)
#pragma unroll
            for (int j = 0; j < 4; j++) acc[i][j] += a[i] * b[j];
    }
#pragma unroll
    for (int i = 0; i < 8; i++) {
        int row = base + r0 + i;
        if (row < M) {
            float4 v = make_float4(fmaxf(acc[i][0], 0.f), fmaxf(acc[i][1], 0.f),
                                   fmaxf(acc[i][2], 0.f), fmaxf(acc[i][3], 0.f));
            *(float4*)(out + (long)row * 64 + c0) = v;
        }
    }
}

// ---------------- Bond encoder: thread-per-edge, chunked layer-1, o[64] accumulators ----
// Max-live regs: in[16] + o[64] + t1[8] ~ 88.  All indices static; weights via uniform s_load.

__global__ __launch_bounds__(256, 2) void k_bond(const float* __restrict__ ea,
        const int* __restrict__ eid_perm,
        const float* __restrict__ W1t, const float* __restrict__ b1,
        const float* __restrict__ W2t, const float* __restrict__ b2,
        __hip_bfloat16* __restrict__ e_out, int E) {
    int e = blockIdx.x * blockDim.x + threadIdx.x;
    if (e >= E) return;
    int src_e = eid_perm[e];
    const float4* er = (const float4*)(ea + (long)src_e * 16);
    float4 q0 = er[0], q1 = er[1], q2 = er[2], q3 = er[3];
    float in[16] = {q0.x, q0.y, q0.z, q0.w, q1.x, q1.y, q1.z, q1.w,
                    q2.x, q2.y, q2.z, q2.w, q3.x, q3.y, q3.z, q3.w};
    float o[64];
#pragma unroll
    for (int j = 0; j < 64; ++j) o[j] = b2[j];
#pragma unroll 1
    for (int kc = 0; kc < 8; ++kc) {
        const float* w1 = W1t + kc * 8 * 16;
        const float* bb = b1 + kc * 8;
        const float* w2 = W2t + kc * 8;
        float t1[8];
#pragma unroll
        for (int j = 0; j < 8; ++j) {
            float a = bb[j];
#pragma unroll
            for (int k = 0; k < 16; ++k) a = fmaf(in[k], w1[j * 16 + k], a);
            t1[j] = fmaxf(a, 0.f);
        }
#pragma unroll
        for (int j = 0; j < 64; ++j) {
#pragma unroll
            for (int k = 0; k < 8; ++k)
                o[j] = fmaf(t1[k], w2[j * 64 + k], o[j]);
        }
    }
    unsigned short* orow = (unsigned short*)e_out + (long)e * 64;
#pragma unroll
    for (int q = 0; q < 8; ++q) {
        uint4 st;
        st.x = f2bf(fmaxf(o[q * 8 + 0], 0.f)) | (f2bf(fmaxf(o[q * 8 + 1], 0.f)) << 16);
        st.y = f2bf(fmaxf(o[q * 8 + 2], 0.f)) | (f2bf(fmaxf(o[q * 8 + 3], 0.f)) << 16);
        st.z = f2bf(fmaxf(o[q * 8 + 4], 0.f)) | (f2bf(fmaxf(o[q * 8 + 5], 0.f)) << 16);
        st.w = f2bf(fmaxf(o[q * 8 + 6], 0.f)) | (f2bf(fmaxf(o[q * 8 + 7], 0.f)) << 16);
        *(uint4*)(orow + q * 8) = st;
    }
}

// ---------------- Aggregation: one wave per node, prefetched src ids, online softmax ------

__global__ __launch_bounds__(256) void k_agg(const float* __restrict__ h,
        const __hip_bfloat16* __restrict__ eperm, const int* __restrict__ sperm,
        const int* __restrict__ row_ptr, const float* __restrict__ t_ptr, int layer,
        float* __restrict__ y, int n) {
    int wid = blockIdx.x * 4 + (threadIdx.x >> 6);
    int lane = threadIdx.x & 63;
    if (wid >= n) return;
    float tval = t_ptr[layer];
    int beg = row_ptr[wid], end = row_ptr[wid + 1];
    float m = -INFINITY, den = 0.f, num = 0.f;
    for (int blk = beg; blk < end; blk += 64) {
        int cnt = min(64, end - blk);
        int sp = sperm[blk + min(lane, cnt - 1)];   // lane-prefetch of up to 64 src ids
        int j = 0;
        if (cnt & 1) {
            int s = __shfl(sp, 0, 64);
            float ev = __bfloat162float(eperm[(long)blk * 64 + lane]);
            float hv = h[(long)s * 64 + lane];
            float msg = fmaxf(hv + ev, 0.f) + 1e-7f;
            float sv = msg * tval;
            float mn = fmaxf(m, sv);
            float sc = __expf(m - mn);
            float w = __expf(sv - mn);
            den = den * sc + w;
            num = num * sc + w * msg;
            m = mn;
            j = 1;
        }
        for (; j < cnt; j += 2) {
            int s0 = __shfl(sp, j, 64);
            int s1 = __shfl(sp, j + 1, 64);
            float ev0 = __bfloat162float(eperm[(long)(blk + j) * 64 + lane]);
            float ev1 = __bfloat162float(eperm[(long)(blk + j + 1) * 64 + lane]);
            float hv0 = h[(long)s0 * 64 + lane];
            float hv1 = h[(long)s1 * 64 + lane];
            float msg0 = fmaxf(hv0 + ev0, 0.f) + 1e-7f;
            float msg1 = fmaxf(hv1 + ev1, 0.f) + 1e-7f;
            float sv0 = msg0 * tval;
            float sv1 = msg1 * tval;
            float mn = fmaxf(fmaxf(m, sv0), sv1);
            float sc = __expf(m - mn);
            float w0 = __expf(sv0 - mn);
            float w1 = __expf(sv1 - mn);
            den = den * sc + w0 + w1;
            num = num * sc + w0 * msg0 + w1 * msg1;
            m = mn;
        }
    }
    float agg = (end > beg) ? num / (den + 1e-16f) : 0.f;
    y[(long)wid * 64 + lane] = h[(long)wid * 64 + lane] + agg;
}

// ---------------- GEMM1 + fused BN partial stats ----------------

__global__ __launch_bounds__(256) void k_gemm1(const float* __restrict__ y,
        const float* __restrict__ W1, const float* __restrict__ b1,
        float* __restrict__ h1, float* __restrict__ part, int n) {
    __shared__ float sA[64][65];
    __shared__ float sW[64 * 128];
    __shared__ float sB[128];
    __shared__ float sS[8][128];
    __shared__ float sS2[8][128];
    int tid = threadIdx.x;
    int base = blockIdx.x * 64;
    for (int i = tid; i < 64 * 128 / 4; i += 256) ((float4*)sW)[i] = ((const float4*)W1)[i];
    if (tid < 128) sB[tid] = b1[tid];
    for (int i = tid; i < 64 * 64 / 4; i += 256) {
        int r = i / 16, c4 = i % 16;
        int row = base + r;
        float4 v = (row < n) ? ((const float4*)(y + (long)row * 64))[c4] : make_float4(0, 0, 0, 0);
        sA[r][c4 * 4 + 0] = v.x; sA[r][c4 * 4 + 1] = v.y;
        sA[r][c4 * 4 + 2] = v.z; sA[r][c4 * 4 + 3] = v.w;
    }
    __syncthreads();
    int rg = tid / 32;
    int r0 = rg * 8;
    int c0 = (tid % 32) * 4;
    float acc[8][4];
#pragma unroll
    for (int i = 0; i < 8; i++)
#pragma unroll
        for (int j = 0; j < 4; j++) acc[i][j] = sB[c0 + j];
    for (int k = 0; k < 64; k++) {
        float a[8], b[4];
#pragma unroll
        for (int i = 0; i < 8; i++) a[i] = sA[r0 + i][k];
#pragma unroll
        for (int j = 0; j < 4; j++) b[j] = sW[k * 128 + c0 + j];
#pragma unroll
        for (int i = 0; i < 8; i++)
#pragma unroll
            for (int j = 0; j < 4; j++) acc[i][j] += a[i] * b[j];
    }
    float ps[4] = {0, 0, 0, 0}, ps2[4] = {0, 0, 0, 0};
#pragma unroll
    for (int i = 0; i < 8; i++) {
        int row = base + r0 + i;
        if (row < n) {
            float4 v = make_float4(acc[i][0], acc[i][1], acc[i][2], acc[i][3]);
            *(float4*)(h1 + (long)row * 128 + c0) = v;
#pragma unroll
            for (int j = 0; j < 4; j++) { ps[j] += acc[i][j]; ps2[j] += acc[i][j] * acc[i][j]; }
        }
    }
#pragma unroll
    for (int j = 0; j < 4; j++) { sS[rg][c0 + j] = ps[j]; sS2[rg][c0 + j] = ps2[j]; }
    __syncthreads();
    if (tid < 128) {
        float s = 0.f, s2 = 0.f;
#pragma unroll
        for (int g = 0; g < 8; g++) { s += sS[g][tid]; s2 += sS2[g][tid]; }
        part[blockIdx.x * 256 + tid] = s;
        part[blockIdx.x * 256 + 128 + tid] = s2;
    }
}

// ---------------- BN reduce: tree stage (64 blocks) then finalize ----------------

__global__ __launch_bounds__(256) void k_bnred(const float* __restrict__ part,
                                               float* __restrict__ part2, int nblk) {
    int c = threadIdx.x;
    int b = blockIdx.x;
    float s = 0.f;
    for (int r = b; r < nblk; r += 64) s += part[r * 256 + c];
    part2[b * 256 + c] = s;
}

__global__ __launch_bounds__(1024) void k_bnfin(const float* __restrict__ part2,
                        const float* __restrict__ gamma, const float* __restrict__ beta,
                        float* __restrict__ scale, float* __restrict__ shift, float invN) {
    __shared__ float red[4][256];
    __shared__ float tot[256];
    int c = threadIdx.x & 255;
    int g = threadIdx.x >> 8;
    float s = 0.f;
#pragma unroll
    for (int r = 0; r < 16; ++r) s += part2[(g * 16 + r) * 256 + c];
    red[g][c] = s;
    __syncthreads();
    if (threadIdx.x < 256) tot[c] = red[0][c] + red[1][c] + red[2][c] + red[3][c];
    __syncthreads();
    if (threadIdx.x < 128) {
        int cc = threadIdx.x;
        float mu = tot[cc] * invN;
        float var = fmaxf(tot[128 + cc] * invN - mu * mu, 0.f);
        float sc = gamma[cc] * rsqrtf(var + 1e-5f);
        scale[cc] = sc;
        shift[cc] = beta[cc] - mu * sc;
    }
}

// ---------------- GEMM2: relu(bn(h1)) @ W2[128,64] + b2 -> hout[N,64] ----------------

__global__ __launch_bounds__(256) void k_gemm2(const float* __restrict__ h1,
        const float* __restrict__ scale, const float* __restrict__ shift,
        const float* __restrict__ W2, const float* __restrict__ b2,
        float* __restrict__ hout, int n, int dorelu) {
    __shared__ float sA[32][129];
    __shared__ float sW[128 * 64];
    __shared__ float sSc[128], sSh[128], sB[64];
    int tid = threadIdx.x;
    int base = blockIdx.x * 32;
    for (int i = tid; i < 128 * 64 / 4; i += 256) ((float4*)sW)[i] = ((const float4*)W2)[i];
    if (tid < 128) { sSc[tid] = scale[tid]; sSh[tid] = shift[tid]; }
    if (tid < 64) sB[tid] = b2[tid];
    __syncthreads();
    for (int i = tid; i < 32 * 128 / 4; i += 256) {
        int r = i / 32, c4 = i % 32;
        int row = base + r;
        float4 v = (row < n) ? ((const float4*)(h1 + (long)row * 128))[c4] : make_float4(0, 0, 0, 0);
        int c = c4 * 4;
        sA[r][c + 0] = fmaxf(v.x * sSc[c + 0] + sSh[c + 0], 0.f);
        sA[r][c + 1] = fmaxf(v.y * sSc[c + 1] + sSh[c + 1], 0.f);
        sA[r][c + 2] = fmaxf(v.z * sSc[c + 2] + sSh[c + 2], 0.f);
        sA[r][c + 3] = fmaxf(v.w * sSc[c + 3] + sSh[c + 3], 0.f);
    }
    __syncthreads();
    int r0 = (tid / 16) * 2;
    int c0 = (tid % 16) * 4;
    float acc[2][4];
#pragma unroll
    for (int i = 0; i < 2; i++)
#pragma unroll
        for (int j = 0; j < 4; j++) acc[i][j] = sB[c0 + j];
    for (int k = 0; k < 128; k++) {
        float a[2], b[4];
#pragma unroll
        for (int i = 0; i < 2; i++) a[i] = sA[r0 + i][k];
#pragma unroll
        for (int j = 0; j < 4; j++) b[j] = sW[k * 64 + c0 + j];
#pragma unroll
        for (int i = 0; i < 2; i++)
#pragma unroll
            for (int j = 0; j < 4; j++) acc[i][j] += a[i] * b[j];
    }
#pragma unroll
    for (int i = 0; i < 2; i++) {
        int row = base + r0 + i;
        if (row < n) {
            float4 v;
            v.x = dorelu ? fmaxf(acc[i][0], 0.f) : acc[i][0];
            v.y = dorelu ? fmaxf(acc[i][1], 0.f) : acc[i][1];
            v.z = dorelu ? fmaxf(acc[i][2], 0.f) : acc[i][2];
            v.w = dorelu ? fmaxf(acc[i][3], 0.f) : acc[i][3];
            *(float4*)(hout + (long)row * 64 + c0) = v;
        }
    }
}

// ---------------- Head: pool per graph + 2-layer MLP to scalar ----------------

__global__ __launch_bounds__(64) void k_head(const float* __restrict__ h,
        const int* __restrict__ gptr,
        const float* __restrict__ W1, const float* __restrict__ b1,
        const float* __restrict__ W2, const float* __restrict__ b2,
        float* __restrict__ out) {
    int g = blockIdx.x;
    int lane = threadIdx.x;
    int beg = gptr[g], end = gptr[g + 1];
    float s = 0.f;
    for (int r = beg; r < end; ++r) s += h[(long)r * 64 + lane];
    __shared__ float sg[64];
    sg[lane] = s;
    __syncthreads();
    float acc = b1[lane];
    for (int k = 0; k < 64; k++) acc += sg[k] * W1[k * 64 + lane];
    acc = fmaxf(acc, 0.f);
    float v = acc * W2[lane];
#pragma unroll
    for (int off = 32; off > 0; off >>= 1) v += __shfl_down(v, off, 64);
    if (lane == 0) out[g] = v + b2[0];
}

// ---------------- launch ----------------

extern "C" void kernel_launch(void* const* d_in, const int* in_sizes, int n_in,
                              void* d_out, int out_size, void* d_ws, size_t ws_size,
                              hipStream_t stream) {
    const float* x      = (const float*)d_in[0];
    const float* ea     = (const float*)d_in[1];
    const int*   ei     = (const int*)d_in[2];
    const int*   batch  = (const int*)d_in[3];
    const float* atomW1 = (const float*)d_in[4];
    const float* atomb1 = (const float*)d_in[5];
    const float* atomW2 = (const float*)d_in[6];
    const float* atomb2 = (const float*)d_in[7];
    const float* bondW1 = (const float*)d_in[8];
    const float* bondb1 = (const float*)d_in[9];
    const float* bondW2 = (const float*)d_in[10];
    const float* bondb2 = (const float*)d_in[11];
    const float* convT  = (const float*)d_in[12];
    const float* convW1 = (const float*)d_in[13];
    const float* convb1 = (const float*)d_in[14];
    const float* convG  = (const float*)d_in[15];
    const float* convBt = (const float*)d_in[16];
    const float* convW2 = (const float*)d_in[17];
    const float* convb2 = (const float*)d_in[18];
    const float* lin1W  = (const float*)d_in[19];
    const float* lin1b  = (const float*)d_in[20];
    const float* lin2W  = (const float*)d_in[21];
    const float* lin2b  = (const float*)d_in[22];
    float* out = (float*)d_out;

    const int N = in_sizes[0] / 32;
    const int E = in_sizes[1] / 16;
    const int G = out_size;
    const int Lconv = in_sizes[12];
    const int nchunk = (N + 1023) / 1024;
    const int nblk1 = (N + 63) / 64;

    size_t need = 0;
    auto count = [&](size_t bytes) { need += (bytes + 255) & ~(size_t)255; };
    count((size_t)E * 64 * 2);
    count((size_t)N * 64 * 4);
    count((size_t)N * 64 * 4);
    count((size_t)N * 128 * 4);
    count((size_t)E * 4);
    count((size_t)E * 4);
    count((size_t)(N + 1) * 4);
    count((size_t)N * 4);
    count((size_t)N * 4);
    count((size_t)(G + 1) * 4);
    count((size_t)nblk1 * 256 * 4);
    count((size_t)64 * 256 * 4);
    count(128 * 4); count(128 * 4);
    count((size_t)(nchunk + 1) * 4);
    count(4);
    count(1024 * 4);
    count(4096 * 4);
    if (ws_size < need) {
        hipMemsetAsync(d_out, 0, (size_t)out_size * 4, stream);
        return;
    }

    char* ws = (char*)d_ws;
    size_t off = 0;
    auto alloc = [&](size_t bytes) -> void* {
        void* p = ws + off;
        off += (bytes + 255) & ~(size_t)255;
        return p;
    };
    __hip_bfloat16* e_perm = (__hip_bfloat16*)alloc((size_t)E * 64 * 2);
    float* h_cur    = (float*)alloc((size_t)N * 64 * 4);
    float* y_buf    = (float*)alloc((size_t)N * 64 * 4);
    float* h1       = (float*)alloc((size_t)N * 128 * 4);
    int*   src_perm = (int*)alloc((size_t)E * 4);
    int*   eid_perm = (int*)alloc((size_t)E * 4);
    int*   row_ptr  = (int*)alloc((size_t)(N + 1) * 4);
    int*   counts   = (int*)alloc((size_t)N * 4);
    int*   fill     = (int*)alloc((size_t)N * 4);
    int*   gptr     = (int*)alloc((size_t)(G + 1) * 4);
    float* part     = (float*)alloc((size_t)nblk1 * 256 * 4);
    float* part2    = (float*)alloc((size_t)64 * 256 * 4);
    float* bnscale  = (float*)alloc(128 * 4);
    float* bnshift  = (float*)alloc(128 * 4);
    int*   csum     = (int*)alloc((size_t)(nchunk + 1) * 4);
    int*   totalp   = (int*)alloc(4);
    float* W1t      = (float*)alloc(1024 * 4);
    float* W2t      = (float*)alloc(4096 * 4);
    (void)n_in;

    hipMemsetAsync(counts, 0, (size_t)N * 4, stream);
    hipMemsetAsync(fill, 0, (size_t)N * 4, stream);

    const int* src = ei;
    const int* dst = ei + E;

    k_hist<<<(E + 255) / 256, 256, 0, stream>>>(dst, counts, E);
    k_scan1<<<nchunk, 1024, 0, stream>>>(counts, row_ptr, csum, N);
    k_scan2<<<1, 64, 0, stream>>>(csum, nchunk, totalp);
    k_scan3<<<(N + 255) / 256, 256, 0, stream>>>(row_ptr, csum, totalp, N);
    k_scatter<<<(E + 255) / 256, 256, 0, stream>>>(src, dst, row_ptr, fill, src_perm, eid_perm, E);
    k_gptr<<<(N + 256) / 256, 256, 0, stream>>>(batch, gptr, N, G);
    k_wt<<<16, 256, 0, stream>>>(bondW1, bondW2, W1t, W2t);

    k_atom<<<(N + TM - 1) / TM, 256, 0, stream>>>(x, atomW1, atomb1, atomW2, atomb2, h_cur, N);
    k_bond<<<(E + 255) / 256, 256, 0, stream>>>(ea, eid_perm, W1t, bondb1, W2t, bondb2, e_perm, E);

    for (int l = 0; l < Lconv; ++l) {
        k_agg<<<(N + 3) / 4, 256, 0, stream>>>(h_cur, e_perm, src_perm, row_ptr, convT, l, y_buf, N);
        k_gemm1<<<nblk1, 256, 0, stream>>>(y_buf, convW1 + (size_t)l * 64 * 128,
                                           convb1 + (size_t)l * 128, h1, part, N);
        k_bnred<<<64, 256, 0, stream>>>(part, part2, nblk1);
        k_bnfin<<<1, 1024, 0, stream>>>(part2, convG + (size_t)l * 128, convBt + (size_t)l * 128,
                                        bnscale, bnshift, 1.0f / (float)N);
        k_gemm2<<<(N + 31) / 32, 256, 0, stream>>>(h1, bnscale, bnshift,
                                                   convW2 + (size_t)l * 128 * 64,
                                                   convb2 + (size_t)l * 64, h_cur, N,
                                                   (l < Lconv - 1) ? 1 : 0);
    }

    k_head<<<G, 64, 0, stream>>>(h_cur, gptr, lin1W, lin1b, lin2W, lin2b, out);
}

// Round 6
// 879.710 us; speedup vs baseline: 1.0874x; 1.0874x over previous
//
#include <hip/hip_runtime.h>
#include <hip/hip_bf16.h>
#include <math.h>

__device__ inline unsigned f2bf(float f) {
    union { __hip_bfloat16 h; unsigned short u; } cv;
    cv.h = __float2bfloat16(f);
    return (unsigned)cv.u;
}

// ---------------- CSR construction ----------------

__global__ void k_hist(const int* __restrict__ dst, int* __restrict__ counts, int E) {
    int e = blockIdx.x * blockDim.x + threadIdx.x;
    if (e < E) atomicAdd(&counts[dst[e]], 1);
}

__global__ void k_scan1(const int* __restrict__ counts, int* __restrict__ row_ptr,
                        int* __restrict__ csum, int n) {
    __shared__ int buf[1024];
    int tid = threadIdx.x;
    int base = blockIdx.x * 1024;
    int v = (base + tid < n) ? counts[base + tid] : 0;
    buf[tid] = v;
    __syncthreads();
    int inc = v;
    for (int off = 1; off < 1024; off <<= 1) {
        int add = (tid >= off) ? buf[tid - off] : 0;
        __syncthreads();
        inc += add;
        buf[tid] = inc;
        __syncthreads();
    }
    if (base + tid < n) row_ptr[base + tid] = inc - v;
    if (tid == 1023) csum[blockIdx.x] = inc;
}

__global__ void k_scan2(int* __restrict__ csum, int nc, int* __restrict__ total) {
    if (threadIdx.x == 0) {
        int run = 0;
        for (int i = 0; i < nc; ++i) { int c = csum[i]; csum[i] = run; run += c; }
        *total = run;
    }
}

__global__ void k_scan3(int* __restrict__ row_ptr, const int* __restrict__ csum,
                        const int* __restrict__ total, int n) {
    int i = blockIdx.x * blockDim.x + threadIdx.x;
    if (i < n) row_ptr[i] += csum[i >> 10];
    if (i == 0) row_ptr[n] = *total;
}

__global__ void k_scatter(const int* __restrict__ src, const int* __restrict__ dst,
                          const int* __restrict__ row_ptr, int* __restrict__ fill,
                          int* __restrict__ src_perm, int* __restrict__ eid_perm, int E) {
    int e = blockIdx.x * blockDim.x + threadIdx.x;
    if (e >= E) return;
    int d = dst[e];
    int pos = row_ptr[d] + atomicAdd(&fill[d], 1);
    src_perm[pos] = src[e];
    eid_perm[pos] = e;
}

__global__ void k_gptr(const int* __restrict__ batch, int* __restrict__ gptr, int n, int G) {
    int i = blockIdx.x * blockDim.x + threadIdx.x;
    if (i > n) return;
    if (i == 0) {
        int b0 = batch[0];
        for (int g = 0; g <= b0; ++g) gptr[g] = 0;
    } else if (i == n) {
        int bl = batch[n - 1];
        for (int g = bl + 1; g <= G; ++g) gptr[g] = n;
    } else {
        int b = batch[i], pb = batch[i - 1];
        for (int g = pb + 1; g <= b; ++g) gptr[g] = i;
    }
}

// ---------------- weight transpose (tiny) ----------------

__global__ void k_wt(const float* __restrict__ W1, const float* __restrict__ W2,
                     float* __restrict__ W1t, float* __restrict__ W2t) {
    int tid = blockIdx.x * blockDim.x + threadIdx.x;
    if (tid < 1024) {
        int j = tid / 16, k = tid % 16;
        W1t[j * 16 + k] = W1[k * 64 + j];
    }
    if (tid < 4096) {
        int j = tid / 64, k = tid % 64;
        W2t[j * 64 + k] = W2[k * 64 + j];
    }
}

// ---------------- Atom encoder: [M,32] -> relu -> [M,64] -> relu ----------------

#define TM 128
__global__ __launch_bounds__(256) void k_atom(const float* __restrict__ x,
        const float* __restrict__ W1, const float* __restrict__ b1,
        const float* __restrict__ W2, const float* __restrict__ b2,
        float* __restrict__ out, int M) {
    __shared__ float sU[TM * 65];
    __shared__ float sW1[32 * 64];
    __shared__ float sW2[64 * 64];
    __shared__ float sB1[64], sB2[64];
#define A_IN(r, c) sU[(r) * 33 + (c)]
#define A_T1(r, c) sU[(r) * 65 + (c)]
    int tid = threadIdx.x;
    int base = blockIdx.x * TM;
    for (int i = tid; i < 32 * 64 / 4; i += 256) ((float4*)sW1)[i] = ((const float4*)W1)[i];
    for (int i = tid; i < 64 * 64 / 4; i += 256) ((float4*)sW2)[i] = ((const float4*)W2)[i];
    if (tid < 64) { sB1[tid] = b1[tid]; sB2[tid] = b2[tid]; }
    for (int i = tid; i < TM * 32 / 4; i += 256) {
        int r = i / 8, c4 = i % 8;
        int row = base + r;
        float4 v = (row < M) ? ((const float4*)(x + (long)row * 32))[c4] : make_float4(0, 0, 0, 0);
        A_IN(r, c4 * 4 + 0) = v.x; A_IN(r, c4 * 4 + 1) = v.y;
        A_IN(r, c4 * 4 + 2) = v.z; A_IN(r, c4 * 4 + 3) = v.w;
    }
    __syncthreads();
    int r0 = (tid / 16) * 8;
    int c0 = (tid % 16) * 4;
    float acc[8][4];
#pragma unroll
    for (int i = 0; i < 8; i++)
#pragma unroll
        for (int j = 0; j < 4; j++) acc[i][j] = sB1[c0 + j];
    for (int k = 0; k < 32; k++) {
        float a[8], b[4];
#pragma unroll
        for (int i = 0; i < 8; i++) a[i] = A_IN(r0 + i, k);
#pragma unroll
        for (int j = 0; j < 4; j++) b[j] = sW1[k * 64 + c0 + j];
#pragma unroll
        for (int i = 0; i < 8; i++)
#pragma unroll
            for (int j = 0; j < 4; j++) acc[i][j] += a[i] * b[j];
    }
    __syncthreads();
#pragma unroll
    for (int i = 0; i < 8; i++)
#pragma unroll
        for (int j = 0; j < 4; j++) A_T1(r0 + i, c0 + j) = fmaxf(acc[i][j], 0.f);
    __syncthreads();
#pragma unroll
    for (int i = 0; i < 8; i++)
#pragma unroll
        for (int j = 0; j < 4; j++) acc[i][j] = sB2[c0 + j];
    for (int k = 0; k < 64; k++) {
        float a[8], b[4];
#pragma unroll
        for (int i = 0; i < 8; i++) a[i] = A_T1(r0 + i, k);
#pragma unroll
        for (int j = 0; j < 4; j++) b[j] = sW2[k * 64 + c0 + j];
#pragma unroll
        for (int i = 0; i < 8; i++)
#pragma unroll
            for (int j = 0; j < 4; j++) acc[i][j] += a[i] * b[j];
    }
#pragma unroll
    for (int i = 0; i < 8; i++) {
        int row = base + r0 + i;
        if (row < M) {
            float4 v = make_float4(fmaxf(acc[i][0], 0.f), fmaxf(acc[i][1], 0.f),
                                   fmaxf(acc[i][2], 0.f), fmaxf(acc[i][3], 0.f));
            *(float4*)(out + (long)row * 64 + c0) = v;
        }
    }
}

// ---------------- Bond encoder: thread-per-edge, FULLY UNROLLED (no loop back-edges) ----
// All array indices compile-time static; weights wave-uniform -> s_load SGPR operands.
// Max live ~ t1[64]+o[64] ~ 135 VGPR. Stores batched at the end (full-line writes).

__global__ __launch_bounds__(256) void k_bond(const float* __restrict__ ea,
        const int* __restrict__ eid_perm,
        const float* __restrict__ W1t, const float* __restrict__ b1,
        const float* __restrict__ W2t, const float* __restrict__ b2,
        __hip_bfloat16* __restrict__ e_out, int E) {
    int e = blockIdx.x * blockDim.x + threadIdx.x;
    if (e >= E) return;
    int src_e = eid_perm[e];
    const float4* er = (const float4*)(ea + (long)src_e * 16);
    float4 q0 = er[0], q1 = er[1], q2 = er[2], q3 = er[3];
    float in[16] = {q0.x, q0.y, q0.z, q0.w, q1.x, q1.y, q1.z, q1.w,
                    q2.x, q2.y, q2.z, q2.w, q3.x, q3.y, q3.z, q3.w};
    float t1[64];
#pragma unroll
    for (int j = 0; j < 64; ++j) {
        float a = b1[j];
#pragma unroll
        for (int k = 0; k < 16; ++k) a = fmaf(in[k], W1t[j * 16 + k], a);
        t1[j] = fmaxf(a, 0.f);
    }
    float o[64];
#pragma unroll
    for (int j = 0; j < 64; ++j) {
        float a = b2[j];
#pragma unroll
        for (int k = 0; k < 64; ++k) a = fmaf(t1[k], W2t[j * 64 + k], a);
        o[j] = fmaxf(a, 0.f);
    }
    unsigned short* orow = (unsigned short*)e_out + (long)e * 64;
#pragma unroll
    for (int q = 0; q < 8; ++q) {
        uint4 st;
        st.x = f2bf(o[q * 8 + 0]) | (f2bf(o[q * 8 + 1]) << 16);
        st.y = f2bf(o[q * 8 + 2]) | (f2bf(o[q * 8 + 3]) << 16);
        st.z = f2bf(o[q * 8 + 4]) | (f2bf(o[q * 8 + 5]) << 16);
        st.w = f2bf(o[q * 8 + 6]) | (f2bf(o[q * 8 + 7]) << 16);
        *(uint4*)(orow + q * 8) = st;
    }
}

// ---------------- Aggregation: one wave per node, prefetched src ids, online softmax ------

__global__ __launch_bounds__(256) void k_agg(const float* __restrict__ h,
        const __hip_bfloat16* __restrict__ eperm, const int* __restrict__ sperm,
        const int* __restrict__ row_ptr, const float* __restrict__ t_ptr, int layer,
        float* __restrict__ y, int n) {
    int wid = blockIdx.x * 4 + (threadIdx.x >> 6);
    int lane = threadIdx.x & 63;
    if (wid >= n) return;
    float tval = t_ptr[layer];
    int beg = row_ptr[wid], end = row_ptr[wid + 1];
    float m = -INFINITY, den = 0.f, num = 0.f;
    for (int blk = beg; blk < end; blk += 64) {
        int cnt = min(64, end - blk);
        int sp = sperm[blk + min(lane, cnt - 1)];
        int j = 0;
        if (cnt & 1) {
            int s = __shfl(sp, 0, 64);
            float ev = __bfloat162float(eperm[(long)blk * 64 + lane]);
            float hv = h[(long)s * 64 + lane];
            float msg = fmaxf(hv + ev, 0.f) + 1e-7f;
            float sv = msg * tval;
            float mn = fmaxf(m, sv);
            float sc = __expf(m - mn);
            float w = __expf(sv - mn);
            den = den * sc + w;
            num = num * sc + w * msg;
            m = mn;
            j = 1;
        }
        for (; j < cnt; j += 2) {
            int s0 = __shfl(sp, j, 64);
            int s1 = __shfl(sp, j + 1, 64);
            float ev0 = __bfloat162float(eperm[(long)(blk + j) * 64 + lane]);
            float ev1 = __bfloat162float(eperm[(long)(blk + j + 1) * 64 + lane]);
            float hv0 = h[(long)s0 * 64 + lane];
            float hv1 = h[(long)s1 * 64 + lane];
            float msg0 = fmaxf(hv0 + ev0, 0.f) + 1e-7f;
            float msg1 = fmaxf(hv1 + ev1, 0.f) + 1e-7f;
            float sv0 = msg0 * tval;
            float sv1 = msg1 * tval;
            float mn = fmaxf(fmaxf(m, sv0), sv1);
            float sc = __expf(m - mn);
            float w0 = __expf(sv0 - mn);
            float w1 = __expf(sv1 - mn);
            den = den * sc + w0 + w1;
            num = num * sc + w0 * msg0 + w1 * msg1;
            m = mn;
        }
    }
    float agg = (end > beg) ? num / (den + 1e-16f) : 0.f;
    y[(long)wid * 64 + lane] = h[(long)wid * 64 + lane] + agg;
}

// ---------------- GEMM1 + fused BN partial stats ----------------

__global__ __launch_bounds__(256) void k_gemm1(const float* __restrict__ y,
        const float* __restrict__ W1, const float* __restrict__ b1,
        float* __restrict__ h1, float* __restrict__ part, int n) {
    __shared__ float sA[64][65];
    __shared__ float sW[64 * 128];
    __shared__ float sB[128];
    __shared__ float sS[8][128];
    __shared__ float sS2[8][128];
    int tid = threadIdx.x;
    int base = blockIdx.x * 64;
    for (int i = tid; i < 64 * 128 / 4; i += 256) ((float4*)sW)[i] = ((const float4*)W1)[i];
    if (tid < 128) sB[tid] = b1[tid];
    for (int i = tid; i < 64 * 64 / 4; i += 256) {
        int r = i / 16, c4 = i % 16;
        int row = base + r;
        float4 v = (row < n) ? ((const float4*)(y + (long)row * 64))[c4] : make_float4(0, 0, 0, 0);
        sA[r][c4 * 4 + 0] = v.x; sA[r][c4 * 4 + 1] = v.y;
        sA[r][c4 * 4 + 2] = v.z; sA[r][c4 * 4 + 3] = v.w;
    }
    __syncthreads();
    int rg = tid / 32;
    int r0 = rg * 8;
    int c0 = (tid % 32) * 4;
    float acc[8][4];
#pragma unroll
    for (int i = 0; i < 8; i++)
#pragma unroll
        for (int j = 0; j < 4; j++) acc[i][j] = sB[c0 + j];
    for (int k = 0; k < 64; k++) {
        float a[8], b[4];
#pragma unroll
        for (int i = 0; i < 8; i++) a[i] = sA[r0 + i][k];
#pragma unroll
        for (int j = 0; j < 4; j++) b[j] = sW[k * 128 + c0 + j];
#pragma unroll
        for (int i = 0; i < 8; i++)
#pragma unroll
            for (int j = 0; j < 4; j++) acc[i][j] += a[i] * b[j];
    }
    float ps[4] = {0, 0, 0, 0}, ps2[4] = {0, 0, 0, 0};
#pragma unroll
    for (int i = 0; i < 8; i++) {
        int row = base + r0 + i;
        if (row < n) {
            float4 v = make_float4(acc[i][0], acc[i][1], acc[i][2], acc[i][3]);
            *(float4*)(h1 + (long)row * 128 + c0) = v;
#pragma unroll
            for (int j = 0; j < 4; j++) { ps[j] += acc[i][j]; ps2[j] += acc[i][j] * acc[i][j]; }
        }
    }
#pragma unroll
    for (int j = 0; j < 4; j++) { sS[rg][c0 + j] = ps[j]; sS2[rg][c0 + j] = ps2[j]; }
    __syncthreads();
    if (tid < 128) {
        float s = 0.f, s2 = 0.f;
#pragma unroll
        for (int g = 0; g < 8; g++) { s += sS[g][tid]; s2 += sS2[g][tid]; }
        part[blockIdx.x * 256 + tid] = s;
        part[blockIdx.x * 256 + 128 + tid] = s2;
    }
}

// ---------------- BN reduce: tree stage (64 blocks) then finalize ----------------

__global__ __launch_bounds__(256) void k_bnred(const float* __restrict__ part,
                                               float* __restrict__ part2, int nblk) {
    int c = threadIdx.x;
    int b = blockIdx.x;
    float s = 0.f;
    for (int r = b; r < nblk; r += 64) s += part[r * 256 + c];
    part2[b * 256 + c] = s;
}

__global__ __launch_bounds__(1024) void k_bnfin(const float* __restrict__ part2,
                        const float* __restrict__ gamma, const float* __restrict__ beta,
                        float* __restrict__ scale, float* __restrict__ shift, float invN) {
    __shared__ float red[4][256];
    __shared__ float tot[256];
    int c = threadIdx.x & 255;
    int g = threadIdx.x >> 8;
    float s = 0.f;
#pragma unroll
    for (int r = 0; r < 16; ++r) s += part2[(g * 16 + r) * 256 + c];
    red[g][c] = s;
    __syncthreads();
    if (threadIdx.x < 256) tot[c] = red[0][c] + red[1][c] + red[2][c] + red[3][c];
    __syncthreads();
    if (threadIdx.x < 128) {
        int cc = threadIdx.x;
        float mu = tot[cc] * invN;
        float var = fmaxf(tot[128 + cc] * invN - mu * mu, 0.f);
        float sc = gamma[cc] * rsqrtf(var + 1e-5f);
        scale[cc] = sc;
        shift[cc] = beta[cc] - mu * sc;
    }
}

// ---------------- GEMM2: relu(bn(h1)) @ W2[128,64] + b2 -> hout[N,64] ----------------

__global__ __launch_bounds__(256) void k_gemm2(const float* __restrict__ h1,
        const float* __restrict__ scale, const float* __restrict__ shift,
        const float* __restrict__ W2, const float* __restrict__ b2,
        float* __restrict__ hout, int n, int dorelu) {
    __shared__ float sA[32][129];
    __shared__ float sW[128 * 64];
    __shared__ float sSc[128], sSh[128], sB[64];
    int tid = threadIdx.x;
    int base = blockIdx.x * 32;
    for (int i = tid; i < 128 * 64 / 4; i += 256) ((float4*)sW)[i] = ((const float4*)W2)[i];
    if (tid < 128) { sSc[tid] = scale[tid]; sSh[tid] = shift[tid]; }
    if (tid < 64) sB[tid] = b2[tid];
    __syncthreads();
    for (int i = tid; i < 32 * 128 / 4; i += 256) {
        int r = i / 32, c4 = i % 32;
        int row = base + r;
        float4 v = (row < n) ? ((const float4*)(h1 + (long)row * 128))[c4] : make_float4(0, 0, 0, 0);
        int c = c4 * 4;
        sA[r][c + 0] = fmaxf(v.x * sSc[c + 0] + sSh[c + 0], 0.f);
        sA[r][c + 1] = fmaxf(v.y * sSc[c + 1] + sSh[c + 1], 0.f);
        sA[r][c + 2] = fmaxf(v.z * sSc[c + 2] + sSh[c + 2], 0.f);
        sA[r][c + 3] = fmaxf(v.w * sSc[c + 3] + sSh[c + 3], 0.f);
    }
    __syncthreads();
    int r0 = (tid / 16) * 2;
    int c0 = (tid % 16) * 4;
    float acc[2][4];
#pragma unroll
    for (int i = 0; i < 2; i++)
#pragma unroll
        for (int j = 0; j < 4; j++) acc[i][j] = sB[c0 + j];
    for (int k = 0; k < 128; k++) {
        float a[2], b[4];
#pragma unroll
        for (int i = 0; i < 2; i++) a[i] = sA[r0 + i][k];
#pragma unroll
        for (int j = 0; j < 4; j++) b[j] = sW[k * 64 + c0 + j];
#pragma unroll
        for (int i = 0; i < 2; i++)
#pragma unroll
            for (int j = 0; j < 4; j++) acc[i][j] += a[i] * b[j];
    }
#pragma unroll
    for (int i = 0; i < 2; i++) {
        int row = base + r0 + i;
        if (row < n) {
            float4 v;
            v.x = dorelu ? fmaxf(acc[i][0], 0.f) : acc[i][0];
            v.y = dorelu ? fmaxf(acc[i][1], 0.f) : acc[i][1];
            v.z = dorelu ? fmaxf(acc[i][2], 0.f) : acc[i][2];
            v.w = dorelu ? fmaxf(acc[i][3], 0.f) : acc[i][3];
            *(float4*)(hout + (long)row * 64 + c0) = v;
        }
    }
}

// ---------------- Head: pool per graph + 2-layer MLP to scalar ----------------

__global__ __launch_bounds__(64) void k_head(const float* __restrict__ h,
        const int* __restrict__ gptr,
        const float* __restrict__ W1, const float* __restrict__ b1,
        const float* __restrict__ W2, const float* __restrict__ b2,
        float* __restrict__ out) {
    int g = blockIdx.x;
    int lane = threadIdx.x;
    int beg = gptr[g], end = gptr[g + 1];
    float s = 0.f;
    for (int r = beg; r < end; ++r) s += h[(long)r * 64 + lane];
    __shared__ float sg[64];
    sg[lane] = s;
    __syncthreads();
    float acc = b1[lane];
    for (int k = 0; k < 64; k++) acc += sg[k] * W1[k * 64 + lane];
    acc = fmaxf(acc, 0.f);
    float v = acc * W2[lane];
#pragma unroll
    for (int off = 32; off > 0; off >>= 1) v += __shfl_down(v, off, 64);
    if (lane == 0) out[g] = v + b2[0];
}

// ---------------- launch ----------------

extern "C" void kernel_launch(void* const* d_in, const int* in_sizes, int n_in,
                              void* d_out, int out_size, void* d_ws, size_t ws_size,
                              hipStream_t stream) {
    const float* x      = (const float*)d_in[0];
    const float* ea     = (const float*)d_in[1];
    const int*   ei     = (const int*)d_in[2];
    const int*   batch  = (const int*)d_in[3];
    const float* atomW1 = (const float*)d_in[4];
    const float* atomb1 = (const float*)d_in[5];
    const float* atomW2 = (const float*)d_in[6];
    const float* atomb2 = (const float*)d_in[7];
    const float* bondW1 = (const float*)d_in[8];
    const float* bondb1 = (const float*)d_in[9];
    const float* bondW2 = (const float*)d_in[10];
    const float* bondb2 = (const float*)d_in[11];
    const float* convT  = (const float*)d_in[12];
    const float* convW1 = (const float*)d_in[13];
    const float* convb1 = (const float*)d_in[14];
    const float* convG  = (const float*)d_in[15];
    const float* convBt = (const float*)d_in[16];
    const float* convW2 = (const float*)d_in[17];
    const float* convb2 = (const float*)d_in[18];
    const float* lin1W  = (const float*)d_in[19];
    const float* lin1b  = (const float*)d_in[20];
    const float* lin2W  = (const float*)d_in[21];
    const float* lin2b  = (const float*)d_in[22];
    float* out = (float*)d_out;

    const int N = in_sizes[0] / 32;
    const int E = in_sizes[1] / 16;
    const int G = out_size;
    const int Lconv = in_sizes[12];
    const int nchunk = (N + 1023) / 1024;
    const int nblk1 = (N + 63) / 64;

    size_t need = 0;
    auto count = [&](size_t bytes) { need += (bytes + 255) & ~(size_t)255; };
    count((size_t)E * 64 * 2);
    count((size_t)N * 64 * 4);
    count((size_t)N * 64 * 4);
    count((size_t)N * 128 * 4);
    count((size_t)E * 4);
    count((size_t)E * 4);
    count((size_t)(N + 1) * 4);
    count((size_t)N * 4);
    count((size_t)N * 4);
    count((size_t)(G + 1) * 4);
    count((size_t)nblk1 * 256 * 4);
    count((size_t)64 * 256 * 4);
    count(128 * 4); count(128 * 4);
    count((size_t)(nchunk + 1) * 4);
    count(4);
    count(1024 * 4);
    count(4096 * 4);
    if (ws_size < need) {
        hipMemsetAsync(d_out, 0, (size_t)out_size * 4, stream);
        return;
    }

    char* ws = (char*)d_ws;
    size_t off = 0;
    auto alloc = [&](size_t bytes) -> void* {
        void* p = ws + off;
        off += (bytes + 255) & ~(size_t)255;
        return p;
    };
    __hip_bfloat16* e_perm = (__hip_bfloat16*)alloc((size_t)E * 64 * 2);
    float* h_cur    = (float*)alloc((size_t)N * 64 * 4);
    float* y_buf    = (float*)alloc((size_t)N * 64 * 4);
    float* h1       = (float*)alloc((size_t)N * 128 * 4);
    int*   src_perm = (int*)alloc((size_t)E * 4);
    int*   eid_perm = (int*)alloc((size_t)E * 4);
    int*   row_ptr  = (int*)alloc((size_t)(N + 1) * 4);
    int*   counts   = (int*)alloc((size_t)N * 4);
    int*   fill     = (int*)alloc((size_t)N * 4);
    int*   gptr     = (int*)alloc((size_t)(G + 1) * 4);
    float* part     = (float*)alloc((size_t)nblk1 * 256 * 4);
    float* part2    = (float*)alloc((size_t)64 * 256 * 4);
    float* bnscale  = (float*)alloc(128 * 4);
    float* bnshift  = (float*)alloc(128 * 4);
    int*   csum     = (int*)alloc((size_t)(nchunk + 1) * 4);
    int*   totalp   = (int*)alloc(4);
    float* W1t      = (float*)alloc(1024 * 4);
    float* W2t      = (float*)alloc(4096 * 4);
    (void)n_in;

    hipMemsetAsync(counts, 0, (size_t)N * 4, stream);
    hipMemsetAsync(fill, 0, (size_t)N * 4, stream);

    const int* src = ei;
    const int* dst = ei + E;

    k_hist<<<(E + 255) / 256, 256, 0, stream>>>(dst, counts, E);
    k_scan1<<<nchunk, 1024, 0, stream>>>(counts, row_ptr, csum, N);
    k_scan2<<<1, 64, 0, stream>>>(csum, nchunk, totalp);
    k_scan3<<<(N + 255) / 256, 256, 0, stream>>>(row_ptr, csum, totalp, N);
    k_scatter<<<(E + 255) / 256, 256, 0, stream>>>(src, dst, row_ptr, fill, src_perm, eid_perm, E);
    k_gptr<<<(N + 256) / 256, 256, 0, stream>>>(batch, gptr, N, G);
    k_wt<<<16, 256, 0, stream>>>(bondW1, bondW2, W1t, W2t);

    k_atom<<<(N + TM - 1) / TM, 256, 0, stream>>>(x, atomW1, atomb1, atomW2, atomb2, h_cur, N);
    k_bond<<<(E + 255) / 256, 256, 0, stream>>>(ea, eid_perm, W1t, bondb1, W2t, bondb2, e_perm, E);

    for (int l = 0; l < Lconv; ++l) {
        k_agg<<<(N + 3) / 4, 256, 0, stream>>>(h_cur, e_perm, src_perm, row_ptr, convT, l, y_buf, N);
        k_gemm1<<<nblk1, 256, 0, stream>>>(y_buf, convW1 + (size_t)l * 64 * 128,
                                           convb1 + (size_t)l * 128, h1, part, N);
        k_bnred<<<64, 256, 0, stream>>>(part, part2, nblk1);
        k_bnfin<<<1, 1024, 0, stream>>>(part2, convG + (size_t)l * 128, convBt + (size_t)l * 128,
                                        bnscale, bnshift, 1.0f / (float)N);
        k_gemm2<<<(N + 31) / 32, 256, 0, stream>>>(h1, bnscale, bnshift,
                                                   convW2 + (size_t)l * 128 * 64,
                                                   convb2 + (size_t)l * 64, h_cur, N,
                                                   (l < Lconv - 1) ? 1 : 0);
    }

    k_head<<<G, 64, 0, stream>>>(h_cur, gptr, lin1W, lin1b, lin2W, lin2b, out);
}

// Round 7
// 679.887 us; speedup vs baseline: 1.4070x; 1.2939x over previous
//
#include <hip/hip_runtime.h>
#include <hip/hip_bf16.h>
#include <math.h>

typedef __attribute__((ext_vector_type(8))) short bf16x8;
typedef __attribute__((ext_vector_type(4))) float f32x4;

__device__ inline unsigned f2bf(float f) {
    union { __hip_bfloat16 h; unsigned short u; } cv;
    cv.h = __float2bfloat16(f);
    return (unsigned)cv.u;
}

// ---------------- CSR construction ----------------

__global__ void k_hist(const int* __restrict__ dst, int* __restrict__ counts, int E) {
    int e = blockIdx.x * blockDim.x + threadIdx.x;
    if (e < E) atomicAdd(&counts[dst[e]], 1);
}

__global__ void k_scan1(const int* __restrict__ counts, int* __restrict__ row_ptr,
                        int* __restrict__ csum, int n) {
    __shared__ int buf[1024];
    int tid = threadIdx.x;
    int base = blockIdx.x * 1024;
    int v = (base + tid < n) ? counts[base + tid] : 0;
    buf[tid] = v;
    __syncthreads();
    int inc = v;
    for (int off = 1; off < 1024; off <<= 1) {
        int add = (tid >= off) ? buf[tid - off] : 0;
        __syncthreads();
        inc += add;
        buf[tid] = inc;
        __syncthreads();
    }
    if (base + tid < n) row_ptr[base + tid] = inc - v;
    if (tid == 1023) csum[blockIdx.x] = inc;
}

__global__ void k_scan2(int* __restrict__ csum, int nc, int* __restrict__ total) {
    if (threadIdx.x == 0) {
        int run = 0;
        for (int i = 0; i < nc; ++i) { int c = csum[i]; csum[i] = run; run += c; }
        *total = run;
    }
}

__global__ void k_scan3(int* __restrict__ row_ptr, const int* __restrict__ csum,
                        const int* __restrict__ total, int n) {
    int i = blockIdx.x * blockDim.x + threadIdx.x;
    if (i < n) row_ptr[i] += csum[i >> 10];
    if (i == 0) row_ptr[n] = *total;
}

__global__ void k_scatter(const int* __restrict__ src, const int* __restrict__ dst,
                          const int* __restrict__ row_ptr, int* __restrict__ fill,
                          int* __restrict__ src_perm, int* __restrict__ eid_perm, int E) {
    int e = blockIdx.x * blockDim.x + threadIdx.x;
    if (e >= E) return;
    int d = dst[e];
    int pos = row_ptr[d] + atomicAdd(&fill[d], 1);
    src_perm[pos] = src[e];
    eid_perm[pos] = e;
}

__global__ void k_gptr(const int* __restrict__ batch, int* __restrict__ gptr, int n, int G) {
    int i = blockIdx.x * blockDim.x + threadIdx.x;
    if (i > n) return;
    if (i == 0) {
        int b0 = batch[0];
        for (int g = 0; g <= b0; ++g) gptr[g] = 0;
    } else if (i == n) {
        int bl = batch[n - 1];
        for (int g = bl + 1; g <= G; ++g) gptr[g] = n;
    } else {
        int b = batch[i], pb = batch[i - 1];
        for (int g = pb + 1; g <= b; ++g) gptr[g] = i;
    }
}

// ---------------- weight transpose (tiny): W1t f32 [64][16], W2tb bf16 [64(N)][64(K)] ----

__global__ void k_wt(const float* __restrict__ W1, const float* __restrict__ W2,
                     float* __restrict__ W1t, unsigned short* __restrict__ W2tb) {
    int tid = blockIdx.x * blockDim.x + threadIdx.x;
    if (tid < 1024) {
        int j = tid / 16, k = tid % 16;
        W1t[j * 16 + k] = W1[k * 64 + j];
    }
    if (tid < 4096) {
        int j = tid / 64, k = tid % 64;
        W2tb[j * 64 + k] = (unsigned short)f2bf(W2[k * 64 + j]);
    }
}

// ---------------- Atom encoder: [M,32] -> relu -> [M,64] -> relu ----------------

#define TM 128
__global__ __launch_bounds__(256) void k_atom(const float* __restrict__ x,
        const float* __restrict__ W1, const float* __restrict__ b1,
        const float* __restrict__ W2, const float* __restrict__ b2,
        float* __restrict__ out, int M) {
    __shared__ float sU[TM * 65];
    __shared__ float sW1[32 * 64];
    __shared__ float sW2[64 * 64];
    __shared__ float sB1[64], sB2[64];
#define A_IN(r, c) sU[(r) * 33 + (c)]
#define A_T1(r, c) sU[(r) * 65 + (c)]
    int tid = threadIdx.x;
    int base = blockIdx.x * TM;
    for (int i = tid; i < 32 * 64 / 4; i += 256) ((float4*)sW1)[i] = ((const float4*)W1)[i];
    for (int i = tid; i < 64 * 64 / 4; i += 256) ((float4*)sW2)[i] = ((const float4*)W2)[i];
    if (tid < 64) { sB1[tid] = b1[tid]; sB2[tid] = b2[tid]; }
    for (int i = tid; i < TM * 32 / 4; i += 256) {
        int r = i / 8, c4 = i % 8;
        int row = base + r;
        float4 v = (row < M) ? ((const float4*)(x + (long)row * 32))[c4] : make_float4(0, 0, 0, 0);
        A_IN(r, c4 * 4 + 0) = v.x; A_IN(r, c4 * 4 + 1) = v.y;
        A_IN(r, c4 * 4 + 2) = v.z; A_IN(r, c4 * 4 + 3) = v.w;
    }
    __syncthreads();
    int r0 = (tid / 16) * 8;
    int c0 = (tid % 16) * 4;
    float acc[8][4];
#pragma unroll
    for (int i = 0; i < 8; i++)
#pragma unroll
        for (int j = 0; j < 4; j++) acc[i][j] = sB1[c0 + j];
    for (int k = 0; k < 32; k++) {
        float a[8], b[4];
#pragma unroll
        for (int i = 0; i < 8; i++) a[i] = A_IN(r0 + i, k);
#pragma unroll
        for (int j = 0; j < 4; j++) b[j] = sW1[k * 64 + c0 + j];
#pragma unroll
        for (int i = 0; i < 8; i++)
#pragma unroll
            for (int j = 0; j < 4; j++) acc[i][j] += a[i] * b[j];
    }
    __syncthreads();
#pragma unroll
    for (int i = 0; i < 8; i++)
#pragma unroll
        for (int j = 0; j < 4; j++) A_T1(r0 + i, c0 + j) = fmaxf(acc[i][j], 0.f);
    __syncthreads();
#pragma unroll
    for (int i = 0; i < 8; i++)
#pragma unroll
        for (int j = 0; j < 4; j++) acc[i][j] = sB2[c0 + j];
    for (int k = 0; k < 64; k++) {
        float a[8], b[4];
#pragma unroll
        for (int i = 0; i < 8; i++) a[i] = A_T1(r0 + i, k);
#pragma unroll
        for (int j = 0; j < 4; j++) b[j] = sW2[k * 64 + c0 + j];
#pragma unroll
        for (int i = 0; i < 8; i++)
#pragma unroll
            for (int j = 0; j < 4; j++) acc[i][j] += a[i] * b[j];
    }
#pragma unroll
    for (int i = 0; i < 8; i++) {
        int row = base + r0 + i;
        if (row < M) {
            float4 v = make_float4(fmaxf(acc[i][0], 0.f), fmaxf(acc[i][1], 0.f),
                                   fmaxf(acc[i][2], 0.f), fmaxf(acc[i][3], 0.f));
            *(float4*)(out + (long)row * 64 + c0) = v;
        }
    }
}

// ---------------- Bond encoder: layer1 f32 per-thread (32 outs), layer2 MFMA bf16 ------
// sT1/sW2 XOR-swizzled ((row&7)<<4 bytes) so ds_read_b128 fragments are conflict-free.
// MFMA frag map (verified m89/m91): A row=lane%16,k=8*(lane/16)+i; B col=lane%16 same k;
// D col=lane%16, row=4*(lane/16)+reg.

__global__ __launch_bounds__(256, 2) void k_bond(const float* __restrict__ ea,
        const int* __restrict__ eid_perm,
        const float* __restrict__ W1t, const float* __restrict__ b1,
        const unsigned short* __restrict__ W2tb, const float* __restrict__ b2,
        __hip_bfloat16* __restrict__ e_out, int E) {
    __shared__ unsigned sT1[128 * 32];   // [row][32 u32] = bf16[128][64], swizzled
    __shared__ unsigned sW2[64 * 32];    // [n][32 u32]   = bf16[64][64] (W2^T), swizzled
    __shared__ float sW1[64 * 16];
    __shared__ float sB1[64], sB2[64];
    int tid = threadIdx.x;

    for (int i = tid; i < 64 * 16 / 4; i += 256) ((float4*)sW1)[i] = ((const float4*)W1t)[i];
    for (int i = tid; i < 2048; i += 256) {
        int rw = i >> 5, cp = i & 31;
        sW2[rw * 32 + (cp ^ ((rw & 7) << 2))] = ((const unsigned*)W2tb)[i];
    }
    if (tid < 64) { sB1[tid] = b1[tid]; sB2[tid] = b2[tid]; }

    int ed = tid & 127, h0 = tid >> 7;
    long gid = (long)blockIdx.x * 128 + ed;
    float in[16];
    if (gid < (long)E) {
        int src_e = eid_perm[gid];
        const float4* er = (const float4*)(ea + (long)src_e * 16);
        float4 q0 = er[0], q1 = er[1], q2 = er[2], q3 = er[3];
        in[0] = q0.x; in[1] = q0.y; in[2] = q0.z; in[3] = q0.w;
        in[4] = q1.x; in[5] = q1.y; in[6] = q1.z; in[7] = q1.w;
        in[8] = q2.x; in[9] = q2.y; in[10] = q2.z; in[11] = q2.w;
        in[12] = q3.x; in[13] = q3.y; in[14] = q3.z; in[15] = q3.w;
    } else {
#pragma unroll
        for (int k = 0; k < 16; ++k) in[k] = 0.f;
    }
    __syncthreads();

    // layer 1: 32 outputs per thread (cols h0*32 .. h0*32+31), f32
    float t[32];
#pragma unroll
    for (int j = 0; j < 32; ++j) {
        float a = sB1[h0 * 32 + j];
#pragma unroll
        for (int k = 0; k < 16; ++k) a = fmaf(in[k], sW1[(h0 * 32 + j) * 16 + k], a);
        t[j] = fmaxf(a, 0.f);
    }
#pragma unroll
    for (int c = 0; c < 16; ++c) {
        unsigned v = f2bf(t[2 * c]) | (f2bf(t[2 * c + 1]) << 16);
        int cp = h0 * 16 + c;
        sT1[ed * 32 + (cp ^ ((ed & 7) << 2))] = v;
    }
    __syncthreads();

    // layer 2: MFMA. wave wv handles M-tiles {2wv, 2wv+1} x all 4 N-tiles, K=64 (2 steps)
    int wv = tid >> 6, lane = tid & 63;
    int lr = lane & 15, q = lane >> 4;
    bf16x8 bf[4][2];
#pragma unroll
    for (int nt = 0; nt < 4; ++nt)
#pragma unroll
        for (int ks = 0; ks < 2; ++ks) {
            int rw = nt * 16 + lr;
            int u = rw * 32 + ((ks * 16 + q * 4) ^ ((rw & 7) << 2));
            bf[nt][ks] = *(const bf16x8*)&sW2[u];
        }
    f32x4 acc[2][4];
#pragma unroll
    for (int mt = 0; mt < 2; ++mt)
#pragma unroll
        for (int nt = 0; nt < 4; ++nt) {
            float bias = sB2[nt * 16 + lr];
            f32x4 c0; c0[0] = bias; c0[1] = bias; c0[2] = bias; c0[3] = bias;
            acc[mt][nt] = c0;
        }
#pragma unroll
    for (int mt = 0; mt < 2; ++mt) {
        int rw = (wv * 2 + mt) * 16 + lr;
#pragma unroll
        for (int ks = 0; ks < 2; ++ks) {
            int u = rw * 32 + ((ks * 16 + q * 4) ^ ((rw & 7) << 2));
            bf16x8 af = *(const bf16x8*)&sT1[u];
#pragma unroll
            for (int nt = 0; nt < 4; ++nt)
                acc[mt][nt] = __builtin_amdgcn_mfma_f32_16x16x32_bf16(
                    af, bf[nt][ks], acc[mt][nt], 0, 0, 0);
        }
    }
    // epilogue: relu + bf16 store.  D: col = lr + nt*16, row_in_tile = q*4 + i
    unsigned short* ob = (unsigned short*)e_out;
#pragma unroll
    for (int mt = 0; mt < 2; ++mt)
#pragma unroll
        for (int nt = 0; nt < 4; ++nt)
#pragma unroll
            for (int i = 0; i < 4; ++i) {
                long row = (long)blockIdx.x * 128 + (wv * 2 + mt) * 16 + q * 4 + i;
                if (row < (long)E)
                    ob[row * 64 + nt * 16 + lr] =
                        (unsigned short)f2bf(fmaxf(acc[mt][nt][i], 0.f));
            }
}

// ---------------- Aggregation: one wave per node, prefetched src ids, online softmax ------

__global__ __launch_bounds__(256) void k_agg(const float* __restrict__ h,
        const __hip_bfloat16* __restrict__ eperm, const int* __restrict__ sperm,
        const int* __restrict__ row_ptr, const float* __restrict__ t_ptr, int layer,
        float* __restrict__ y, int n) {
    int wid = blockIdx.x * 4 + (threadIdx.x >> 6);
    int lane = threadIdx.x & 63;
    if (wid >= n) return;
    float tval = t_ptr[layer];
    int beg = row_ptr[wid], end = row_ptr[wid + 1];
    float m = -INFINITY, den = 0.f, num = 0.f;
    for (int blk = beg; blk < end; blk += 64) {
        int cnt = min(64, end - blk);
        int sp = sperm[blk + min(lane, cnt - 1)];
        int j = 0;
        if (cnt & 1) {
            int s = __shfl(sp, 0, 64);
            float ev = __bfloat162float(eperm[(long)blk * 64 + lane]);
            float hv = h[(long)s * 64 + lane];
            float msg = fmaxf(hv + ev, 0.f) + 1e-7f;
            float sv = msg * tval;
            float mn = fmaxf(m, sv);
            float sc = __expf(m - mn);
            float w = __expf(sv - mn);
            den = den * sc + w;
            num = num * sc + w * msg;
            m = mn;
            j = 1;
        }
        for (; j < cnt; j += 2) {
            int s0 = __shfl(sp, j, 64);
            int s1 = __shfl(sp, j + 1, 64);
            float ev0 = __bfloat162float(eperm[(long)(blk + j) * 64 + lane]);
            float ev1 = __bfloat162float(eperm[(long)(blk + j + 1) * 64 + lane]);
            float hv0 = h[(long)s0 * 64 + lane];
            float hv1 = h[(long)s1 * 64 + lane];
            float msg0 = fmaxf(hv0 + ev0, 0.f) + 1e-7f;
            float msg1 = fmaxf(hv1 + ev1, 0.f) + 1e-7f;
            float sv0 = msg0 * tval;
            float sv1 = msg1 * tval;
            float mn = fmaxf(fmaxf(m, sv0), sv1);
            float sc = __expf(m - mn);
            float w0 = __expf(sv0 - mn);
            float w1 = __expf(sv1 - mn);
            den = den * sc + w0 + w1;
            num = num * sc + w0 * msg0 + w1 * msg1;
            m = mn;
        }
    }
    float agg = (end > beg) ? num / (den + 1e-16f) : 0.f;
    y[(long)wid * 64 + lane] = h[(long)wid * 64 + lane] + agg;
}

// ---------------- GEMM1 + fused BN partial stats ----------------

__global__ __launch_bounds__(256) void k_gemm1(const float* __restrict__ y,
        const float* __restrict__ W1, const float* __restrict__ b1,
        float* __restrict__ h1, float* __restrict__ part, int n) {
    __shared__ float sA[64][65];
    __shared__ float sW[64 * 128];
    __shared__ float sB[128];
    __shared__ float sS[8][128];
    __shared__ float sS2[8][128];
    int tid = threadIdx.x;
    int base = blockIdx.x * 64;
    for (int i = tid; i < 64 * 128 / 4; i += 256) ((float4*)sW)[i] = ((const float4*)W1)[i];
    if (tid < 128) sB[tid] = b1[tid];
    for (int i = tid; i < 64 * 64 / 4; i += 256) {
        int r = i / 16, c4 = i % 16;
        int row = base + r;
        float4 v = (row < n) ? ((const float4*)(y + (long)row * 64))[c4] : make_float4(0, 0, 0, 0);
        sA[r][c4 * 4 + 0] = v.x; sA[r][c4 * 4 + 1] = v.y;
        sA[r][c4 * 4 + 2] = v.z; sA[r][c4 * 4 + 3] = v.w;
    }
    __syncthreads();
    int rg = tid / 32;
    int r0 = rg * 8;
    int c0 = (tid % 32) * 4;
    float acc[8][4];
#pragma unroll
    for (int i = 0; i < 8; i++)
#pragma unroll
        for (int j = 0; j < 4; j++) acc[i][j] = sB[c0 + j];
    for (int k = 0; k < 64; k++) {
        float a[8], b[4];
#pragma unroll
        for (int i = 0; i < 8; i++) a[i] = sA[r0 + i][k];
#pragma unroll
        for (int j = 0; j < 4; j++) b[j] = sW[k * 128 + c0 + j];
#pragma unroll
        for (int i = 0; i < 8; i++)
#pragma unroll
            for (int j = 0; j < 4; j++) acc[i][j] += a[i] * b[j];
    }
    float ps[4] = {0, 0, 0, 0}, ps2[4] = {0, 0, 0, 0};
#pragma unroll
    for (int i = 0; i < 8; i++) {
        int row = base + r0 + i;
        if (row < n) {
            float4 v = make_float4(acc[i][0], acc[i][1], acc[i][2], acc[i][3]);
            *(float4*)(h1 + (long)row * 128 + c0) = v;
#pragma unroll
            for (int j = 0; j < 4; j++) { ps[j] += acc[i][j]; ps2[j] += acc[i][j] * acc[i][j]; }
        }
    }
#pragma unroll
    for (int j = 0; j < 4; j++) { sS[rg][c0 + j] = ps[j]; sS2[rg][c0 + j] = ps2[j]; }
    __syncthreads();
    if (tid < 128) {
        float s = 0.f, s2 = 0.f;
#pragma unroll
        for (int g = 0; g < 8; g++) { s += sS[g][tid]; s2 += sS2[g][tid]; }
        part[blockIdx.x * 256 + tid] = s;
        part[blockIdx.x * 256 + 128 + tid] = s2;
    }
}

// ---------------- BN reduce: tree stage (64 blocks) then finalize ----------------

__global__ __launch_bounds__(256) void k_bnred(const float* __restrict__ part,
                                               float* __restrict__ part2, int nblk) {
    int c = threadIdx.x;
    int b = blockIdx.x;
    float s = 0.f;
    for (int r = b; r < nblk; r += 64) s += part[r * 256 + c];
    part2[b * 256 + c] = s;
}

__global__ __launch_bounds__(1024) void k_bnfin(const float* __restrict__ part2,
                        const float* __restrict__ gamma, const float* __restrict__ beta,
                        float* __restrict__ scale, float* __restrict__ shift, float invN) {
    __shared__ float red[4][256];
    __shared__ float tot[256];
    int c = threadIdx.x & 255;
    int g = threadIdx.x >> 8;
    float s = 0.f;
#pragma unroll
    for (int r = 0; r < 16; ++r) s += part2[(g * 16 + r) * 256 + c];
    red[g][c] = s;
    __syncthreads();
    if (threadIdx.x < 256) tot[c] = red[0][c] + red[1][c] + red[2][c] + red[3][c];
    __syncthreads();
    if (threadIdx.x < 128) {
        int cc = threadIdx.x;
        float mu = tot[cc] * invN;
        float var = fmaxf(tot[128 + cc] * invN - mu * mu, 0.f);
        float sc = gamma[cc] * rsqrtf(var + 1e-5f);
        scale[cc] = sc;
        shift[cc] = beta[cc] - mu * sc;
    }
}

// ---------------- GEMM2: relu(bn(h1)) @ W2[128,64] + b2 -> hout[N,64] ----------------

__global__ __launch_bounds__(256) void k_gemm2(const float* __restrict__ h1,
        const float* __restrict__ scale, const float* __restrict__ shift,
        const float* __restrict__ W2, const float* __restrict__ b2,
        float* __restrict__ hout, int n, int dorelu) {
    __shared__ float sA[32][129];
    __shared__ float sW[128 * 64];
    __shared__ float sSc[128], sSh[128], sB[64];
    int tid = threadIdx.x;
    int base = blockIdx.x * 32;
    for (int i = tid; i < 128 * 64 / 4; i += 256) ((float4*)sW)[i] = ((const float4*)W2)[i];
    if (tid < 128) { sSc[tid] = scale[tid]; sSh[tid] = shift[tid]; }
    if (tid < 64) sB[tid] = b2[tid];
    __syncthreads();
    for (int i = tid; i < 32 * 128 / 4; i += 256) {
        int r = i / 32, c4 = i % 32;
        int row = base + r;
        float4 v = (row < n) ? ((const float4*)(h1 + (long)row * 128))[c4] : make_float4(0, 0, 0, 0);
        int c = c4 * 4;
        sA[r][c + 0] = fmaxf(v.x * sSc[c + 0] + sSh[c + 0], 0.f);
        sA[r][c + 1] = fmaxf(v.y * sSc[c + 1] + sSh[c + 1], 0.f);
        sA[r][c + 2] = fmaxf(v.z * sSc[c + 2] + sSh[c + 2], 0.f);
        sA[r][c + 3] = fmaxf(v.w * sSc[c + 3] + sSh[c + 3], 0.f);
    }
    __syncthreads();
    int r0 = (tid / 16) * 2;
    int c0 = (tid % 16) * 4;
    float acc[2][4];
#pragma unroll
    for (int i = 0; i < 2; i++)
#pragma unroll
        for (int j = 0; j < 4; j++) acc[i][j] = sB[c0 + j];
    for (int k = 0; k < 128; k++) {
        float a[2], b[4];
#pragma unroll
        for (int i = 0; i < 2; i++) a[i] = sA[r0 + i][k];
#pragma unroll
        for (int j = 0; j < 4; j++) b[j] = sW[k * 64 + c0 + j];
#pragma unroll
        for (int i = 0; i < 2; i++)
#pragma unroll
            for (int j = 0; j < 4; j++) acc[i][j] += a[i] * b[j];
    }
#pragma unroll
    for (int i = 0; i < 2; i++) {
        int row = base + r0 + i;
        if (row < n) {
            float4 v;
            v.x = dorelu ? fmaxf(acc[i][0], 0.f) : acc[i][0];
            v.y = dorelu ? fmaxf(acc[i][1], 0.f) : acc[i][1];
            v.z = dorelu ? fmaxf(acc[i][2], 0.f) : acc[i][2];
            v.w = dorelu ? fmaxf(acc[i][3], 0.f) : acc[i][3];
            *(float4*)(hout + (long)row * 64 + c0) = v;
        }
    }
}

// ---------------- Head: pool per graph + 2-layer MLP to scalar ----------------

__global__ __launch_bounds__(64) void k_head(const float* __restrict__ h,
        const int* __restrict__ gptr,
        const float* __restrict__ W1, const float* __restrict__ b1,
        const float* __restrict__ W2, const float* __restrict__ b2,
        float* __restrict__ out) {
    int g = blockIdx.x;
    int lane = threadIdx.x;
    int beg = gptr[g], end = gptr[g + 1];
    float s = 0.f;
    for (int r = beg; r < end; ++r) s += h[(long)r * 64 + lane];
    __shared__ float sg[64];
    sg[lane] = s;
    __syncthreads();
    float acc = b1[lane];
    for (int k = 0; k < 64; k++) acc += sg[k] * W1[k * 64 + lane];
    acc = fmaxf(acc, 0.f);
    float v = acc * W2[lane];
#pragma unroll
    for (int off = 32; off > 0; off >>= 1) v += __shfl_down(v, off, 64);
    if (lane == 0) out[g] = v + b2[0];
}

// ---------------- launch ----------------

extern "C" void kernel_launch(void* const* d_in, const int* in_sizes, int n_in,
                              void* d_out, int out_size, void* d_ws, size_t ws_size,
                              hipStream_t stream) {
    const float* x      = (const float*)d_in[0];
    const float* ea     = (const float*)d_in[1];
    const int*   ei     = (const int*)d_in[2];
    const int*   batch  = (const int*)d_in[3];
    const float* atomW1 = (const float*)d_in[4];
    const float* atomb1 = (const float*)d_in[5];
    const float* atomW2 = (const float*)d_in[6];
    const float* atomb2 = (const float*)d_in[7];
    const float* bondW1 = (const float*)d_in[8];
    const float* bondb1 = (const float*)d_in[9];
    const float* bondW2 = (const float*)d_in[10];
    const float* bondb2 = (const float*)d_in[11];
    const float* convT  = (const float*)d_in[12];
    const float* convW1 = (const float*)d_in[13];
    const float* convb1 = (const float*)d_in[14];
    const float* convG  = (const float*)d_in[15];
    const float* convBt = (const float*)d_in[16];
    const float* convW2 = (const float*)d_in[17];
    const float* convb2 = (const float*)d_in[18];
    const float* lin1W  = (const float*)d_in[19];
    const float* lin1b  = (const float*)d_in[20];
    const float* lin2W  = (const float*)d_in[21];
    const float* lin2b  = (const float*)d_in[22];
    float* out = (float*)d_out;

    const int N = in_sizes[0] / 32;
    const int E = in_sizes[1] / 16;
    const int G = out_size;
    const int Lconv = in_sizes[12];
    const int nchunk = (N + 1023) / 1024;
    const int nblk1 = (N + 63) / 64;

    size_t need = 0;
    auto count = [&](size_t bytes) { need += (bytes + 255) & ~(size_t)255; };
    count((size_t)E * 64 * 2);
    count((size_t)N * 64 * 4);
    count((size_t)N * 64 * 4);
    count((size_t)N * 128 * 4);
    count((size_t)E * 4);
    count((size_t)E * 4);
    count((size_t)(N + 1) * 4);
    count((size_t)N * 4);
    count((size_t)N * 4);
    count((size_t)(G + 1) * 4);
    count((size_t)nblk1 * 256 * 4);
    count((size_t)64 * 256 * 4);
    count(128 * 4); count(128 * 4);
    count((size_t)(nchunk + 1) * 4);
    count(4);
    count(1024 * 4);
    count(4096 * 2);
    if (ws_size < need) {
        hipMemsetAsync(d_out, 0, (size_t)out_size * 4, stream);
        return;
    }

    char* ws = (char*)d_ws;
    size_t off = 0;
    auto alloc = [&](size_t bytes) -> void* {
        void* p = ws + off;
        off += (bytes + 255) & ~(size_t)255;
        return p;
    };
    __hip_bfloat16* e_perm = (__hip_bfloat16*)alloc((size_t)E * 64 * 2);
    float* h_cur    = (float*)alloc((size_t)N * 64 * 4);
    float* y_buf    = (float*)alloc((size_t)N * 64 * 4);
    float* h1       = (float*)alloc((size_t)N * 128 * 4);
    int*   src_perm = (int*)alloc((size_t)E * 4);
    int*   eid_perm = (int*)alloc((size_t)E * 4);
    int*   row_ptr  = (int*)alloc((size_t)(N + 1) * 4);
    int*   counts   = (int*)alloc((size_t)N * 4);
    int*   fill     = (int*)alloc((size_t)N * 4);
    int*   gptr     = (int*)alloc((size_t)(G + 1) * 4);
    float* part     = (float*)alloc((size_t)nblk1 * 256 * 4);
    float* part2    = (float*)alloc((size_t)64 * 256 * 4);
    float* bnscale  = (float*)alloc(128 * 4);
    float* bnshift  = (float*)alloc(128 * 4);
    int*   csum     = (int*)alloc((size_t)(nchunk + 1) * 4);
    int*   totalp   = (int*)alloc(4);
    float* W1t      = (float*)alloc(1024 * 4);
    unsigned short* W2tb = (unsigned short*)alloc(4096 * 2);
    (void)n_in;

    hipMemsetAsync(counts, 0, (size_t)N * 4, stream);
    hipMemsetAsync(fill, 0, (size_t)N * 4, stream);

    const int* src = ei;
    const int* dst = ei + E;

    k_hist<<<(E + 255) / 256, 256, 0, stream>>>(dst, counts, E);
    k_scan1<<<nchunk, 1024, 0, stream>>>(counts, row_ptr, csum, N);
    k_scan2<<<1, 64, 0, stream>>>(csum, nchunk, totalp);
    k_scan3<<<(N + 255) / 256, 256, 0, stream>>>(row_ptr, csum, totalp, N);
    k_scatter<<<(E + 255) / 256, 256, 0, stream>>>(src, dst, row_ptr, fill, src_perm, eid_perm, E);
    k_gptr<<<(N + 256) / 256, 256, 0, stream>>>(batch, gptr, N, G);
    k_wt<<<16, 256, 0, stream>>>(bondW1, bondW2, W1t, W2tb);

    k_atom<<<(N + TM - 1) / TM, 256, 0, stream>>>(x, atomW1, atomb1, atomW2, atomb2, h_cur, N);
    k_bond<<<(E + 127) / 128, 256, 0, stream>>>(ea, eid_perm, W1t, bondb1, W2tb, bondb2,
                                                e_perm, E);

    for (int l = 0; l < Lconv; ++l) {
        k_agg<<<(N + 3) / 4, 256, 0, stream>>>(h_cur, e_perm, src_perm, row_ptr, convT, l, y_buf, N);
        k_gemm1<<<nblk1, 256, 0, stream>>>(y_buf, convW1 + (size_t)l * 64 * 128,
                                           convb1 + (size_t)l * 128, h1, part, N);
        k_bnred<<<64, 256, 0, stream>>>(part, part2, nblk1);
        k_bnfin<<<1, 1024, 0, stream>>>(part2, convG + (size_t)l * 128, convBt + (size_t)l * 128,
                                        bnscale, bnshift, 1.0f / (float)N);
        k_gemm2<<<(N + 31) / 32, 256, 0, stream>>>(h1, bnscale, bnshift,
                                                   convW2 + (size_t)l * 128 * 64,
                                                   convb2 + (size_t)l * 64, h_cur, N,
                                                   (l < Lconv - 1) ? 1 : 0);
    }

    k_head<<<G, 64, 0, stream>>>(h_cur, gptr, lin1W, lin1b, lin2W, lin2b, out);
}

// Round 8
// 669.934 us; speedup vs baseline: 1.4279x; 1.0149x over previous
//
#include <hip/hip_runtime.h>
#include <hip/hip_bf16.h>
#include <math.h>

typedef __attribute__((ext_vector_type(8))) short bf16x8;
typedef __attribute__((ext_vector_type(4))) float f32x4;

__device__ inline unsigned f2bf(float f) {
    union { __hip_bfloat16 h; unsigned short u; } cv;
    cv.h = __float2bfloat16(f);
    return (unsigned)cv.u;
}

// ---------------- CSR construction ----------------

__global__ void k_hist(const int* __restrict__ dst, int* __restrict__ counts, int E) {
    int e = blockIdx.x * blockDim.x + threadIdx.x;
    if (e < E) atomicAdd(&counts[dst[e]], 1);
}

__global__ void k_scan1(const int* __restrict__ counts, int* __restrict__ row_ptr,
                        int* __restrict__ csum, int n) {
    __shared__ int buf[1024];
    int tid = threadIdx.x;
    int base = blockIdx.x * 1024;
    int v = (base + tid < n) ? counts[base + tid] : 0;
    buf[tid] = v;
    __syncthreads();
    int inc = v;
    for (int off = 1; off < 1024; off <<= 1) {
        int add = (tid >= off) ? buf[tid - off] : 0;
        __syncthreads();
        inc += add;
        buf[tid] = inc;
        __syncthreads();
    }
    if (base + tid < n) row_ptr[base + tid] = inc - v;
    if (tid == 1023) csum[blockIdx.x] = inc;
}

__global__ void k_scan2(int* __restrict__ csum, int nc, int* __restrict__ total) {
    if (threadIdx.x == 0) {
        int run = 0;
        for (int i = 0; i < nc; ++i) { int c = csum[i]; csum[i] = run; run += c; }
        *total = run;
    }
}

__global__ void k_scan3(int* __restrict__ row_ptr, const int* __restrict__ csum,
                        const int* __restrict__ total, int n) {
    int i = blockIdx.x * blockDim.x + threadIdx.x;
    if (i < n) row_ptr[i] += csum[i >> 10];
    if (i == 0) row_ptr[n] = *total;
}

__global__ void k_scatter(const int* __restrict__ src, const int* __restrict__ dst,
                          const int* __restrict__ row_ptr, int* __restrict__ fill,
                          int* __restrict__ src_perm, int* __restrict__ eid_perm, int E) {
    int e = blockIdx.x * blockDim.x + threadIdx.x;
    if (e >= E) return;
    int d = dst[e];
    int pos = row_ptr[d] + atomicAdd(&fill[d], 1);
    src_perm[pos] = src[e];
    eid_perm[pos] = e;
}

__global__ void k_gptr(const int* __restrict__ batch, int* __restrict__ gptr, int n, int G) {
    int i = blockIdx.x * blockDim.x + threadIdx.x;
    if (i > n) return;
    if (i == 0) {
        int b0 = batch[0];
        for (int g = 0; g <= b0; ++g) gptr[g] = 0;
    } else if (i == n) {
        int bl = batch[n - 1];
        for (int g = bl + 1; g <= G; ++g) gptr[g] = n;
    } else {
        int b = batch[i], pb = batch[i - 1];
        for (int g = pb + 1; g <= b; ++g) gptr[g] = i;
    }
}

// ---------------- weight transpose (tiny): W1t f32 [64][16], W2tb bf16 [64(N)][64(K)] ----

__global__ void k_wt(const float* __restrict__ W1, const float* __restrict__ W2,
                     float* __restrict__ W1t, unsigned short* __restrict__ W2tb) {
    int tid = blockIdx.x * blockDim.x + threadIdx.x;
    if (tid < 1024) {
        int j = tid / 16, k = tid % 16;
        W1t[j * 16 + k] = W1[k * 64 + j];
    }
    if (tid < 4096) {
        int j = tid / 64, k = tid % 64;
        W2tb[j * 64 + k] = (unsigned short)f2bf(W2[k * 64 + j]);
    }
}

// ---------------- Atom encoder: [M,32] -> relu -> [M,64] -> relu ----------------

#define TM 128
__global__ __launch_bounds__(256) void k_atom(const float* __restrict__ x,
        const float* __restrict__ W1, const float* __restrict__ b1,
        const float* __restrict__ W2, const float* __restrict__ b2,
        float* __restrict__ out, int M) {
    __shared__ float sU[TM * 65];
    __shared__ float sW1[32 * 64];
    __shared__ float sW2[64 * 64];
    __shared__ float sB1[64], sB2[64];
#define A_IN(r, c) sU[(r) * 33 + (c)]
#define A_T1(r, c) sU[(r) * 65 + (c)]
    int tid = threadIdx.x;
    int base = blockIdx.x * TM;
    for (int i = tid; i < 32 * 64 / 4; i += 256) ((float4*)sW1)[i] = ((const float4*)W1)[i];
    for (int i = tid; i < 64 * 64 / 4; i += 256) ((float4*)sW2)[i] = ((const float4*)W2)[i];
    if (tid < 64) { sB1[tid] = b1[tid]; sB2[tid] = b2[tid]; }
    for (int i = tid; i < TM * 32 / 4; i += 256) {
        int r = i / 8, c4 = i % 8;
        int row = base + r;
        float4 v = (row < M) ? ((const float4*)(x + (long)row * 32))[c4] : make_float4(0, 0, 0, 0);
        A_IN(r, c4 * 4 + 0) = v.x; A_IN(r, c4 * 4 + 1) = v.y;
        A_IN(r, c4 * 4 + 2) = v.z; A_IN(r, c4 * 4 + 3) = v.w;
    }
    __syncthreads();
    int r0 = (tid / 16) * 8;
    int c0 = (tid % 16) * 4;
    float acc[8][4];
#pragma unroll
    for (int i = 0; i < 8; i++)
#pragma unroll
        for (int j = 0; j < 4; j++) acc[i][j] = sB1[c0 + j];
    for (int k = 0; k < 32; k++) {
        float a[8], b[4];
#pragma unroll
        for (int i = 0; i < 8; i++) a[i] = A_IN(r0 + i, k);
#pragma unroll
        for (int j = 0; j < 4; j++) b[j] = sW1[k * 64 + c0 + j];
#pragma unroll
        for (int i = 0; i < 8; i++)
#pragma unroll
            for (int j = 0; j < 4; j++) acc[i][j] += a[i] * b[j];
    }
    __syncthreads();
#pragma unroll
    for (int i = 0; i < 8; i++)
#pragma unroll
        for (int j = 0; j < 4; j++) A_T1(r0 + i, c0 + j) = fmaxf(acc[i][j], 0.f);
    __syncthreads();
#pragma unroll
    for (int i = 0; i < 8; i++)
#pragma unroll
        for (int j = 0; j < 4; j++) acc[i][j] = sB2[c0 + j];
    for (int k = 0; k < 64; k++) {
        float a[8], b[4];
#pragma unroll
        for (int i = 0; i < 8; i++) a[i] = A_T1(r0 + i, k);
#pragma unroll
        for (int j = 0; j < 4; j++) b[j] = sW2[k * 64 + c0 + j];
#pragma unroll
        for (int i = 0; i < 8; i++)
#pragma unroll
            for (int j = 0; j < 4; j++) acc[i][j] += a[i] * b[j];
    }
#pragma unroll
    for (int i = 0; i < 8; i++) {
        int row = base + r0 + i;
        if (row < M) {
            float4 v = make_float4(fmaxf(acc[i][0], 0.f), fmaxf(acc[i][1], 0.f),
                                   fmaxf(acc[i][2], 0.f), fmaxf(acc[i][3], 0.f));
            *(float4*)(out + (long)row * 64 + c0) = v;
        }
    }
}

// ---------------- Bond encoder: layer1 f32 (weights via wave-uniform s_load), layer2 MFMA -
// sT1/sW2 XOR-swizzled ((row&7)<<4 bytes) for conflict-free ds_read_b128.

__global__ __launch_bounds__(256) void k_bond(const float* __restrict__ ea,
        const int* __restrict__ eid_perm,
        const float* __restrict__ W1t, const float* __restrict__ b1,
        const unsigned short* __restrict__ W2tb, const float* __restrict__ b2,
        __hip_bfloat16* __restrict__ e_out, int E) {
    __shared__ unsigned sT1[128 * 32];   // bf16[128][64], swizzled
    __shared__ unsigned sW2[64 * 32];    // bf16[64][64] (W2^T), swizzled
    int tid = threadIdx.x;

    for (int i = tid; i < 2048; i += 256) {
        int rw = i >> 5, cp = i & 31;
        sW2[rw * 32 + (cp ^ ((rw & 7) << 2))] = ((const unsigned*)W2tb)[i];
    }

    int ed = tid & 127;
    int h0 = __builtin_amdgcn_readfirstlane(tid >> 7);   // wave-uniform half index
    long gid = (long)blockIdx.x * 128 + ed;
    float in[16];
    if (gid < (long)E) {
        int src_e = eid_perm[gid];
        const float4* er = (const float4*)(ea + (long)src_e * 16);
        float4 q0 = er[0], q1 = er[1], q2 = er[2], q3 = er[3];
        in[0] = q0.x; in[1] = q0.y; in[2] = q0.z; in[3] = q0.w;
        in[4] = q1.x; in[5] = q1.y; in[6] = q1.z; in[7] = q1.w;
        in[8] = q2.x; in[9] = q2.y; in[10] = q2.z; in[11] = q2.w;
        in[12] = q3.x; in[13] = q3.y; in[14] = q3.z; in[15] = q3.w;
    } else {
#pragma unroll
        for (int k = 0; k < 16; ++k) in[k] = 0.f;
    }

    // layer 1: 32 outputs per thread; weights from GLOBAL with uniform index -> s_load.
    // pack interleaved so only 2 accumulators live at a time.
#pragma unroll
    for (int c = 0; c < 16; ++c) {
        float a0 = b1[h0 * 32 + 2 * c];
        float a1 = b1[h0 * 32 + 2 * c + 1];
#pragma unroll
        for (int k = 0; k < 16; ++k) {
            a0 = fmaf(in[k], W1t[(h0 * 32 + 2 * c) * 16 + k], a0);
            a1 = fmaf(in[k], W1t[(h0 * 32 + 2 * c + 1) * 16 + k], a1);
        }
        unsigned v = f2bf(fmaxf(a0, 0.f)) | (f2bf(fmaxf(a1, 0.f)) << 16);
        int cp = h0 * 16 + c;
        sT1[ed * 32 + (cp ^ ((ed & 7) << 2))] = v;
    }
    __syncthreads();

    // layer 2: MFMA. wave wv: M-tiles {2wv,2wv+1} x 4 N-tiles, K=64 (2 steps)
    int wv = tid >> 6, lane = tid & 63;
    int lr = lane & 15, q = lane >> 4;
    bf16x8 bf[4][2];
#pragma unroll
    for (int nt = 0; nt < 4; ++nt)
#pragma unroll
        for (int ks = 0; ks < 2; ++ks) {
            int rw = nt * 16 + lr;
            int u = rw * 32 + ((ks * 16 + q * 4) ^ ((rw & 7) << 2));
            bf[nt][ks] = *(const bf16x8*)&sW2[u];
        }
    f32x4 acc[2][4];
#pragma unroll
    for (int mt = 0; mt < 2; ++mt)
#pragma unroll
        for (int nt = 0; nt < 4; ++nt) {
            float bias = b2[nt * 16 + lr];
            f32x4 c0; c0[0] = bias; c0[1] = bias; c0[2] = bias; c0[3] = bias;
            acc[mt][nt] = c0;
        }
#pragma unroll
    for (int mt = 0; mt < 2; ++mt) {
        int rw = (wv * 2 + mt) * 16 + lr;
#pragma unroll
        for (int ks = 0; ks < 2; ++ks) {
            int u = rw * 32 + ((ks * 16 + q * 4) ^ ((rw & 7) << 2));
            bf16x8 af = *(const bf16x8*)&sT1[u];
#pragma unroll
            for (int nt = 0; nt < 4; ++nt)
                acc[mt][nt] = __builtin_amdgcn_mfma_f32_16x16x32_bf16(
                    af, bf[nt][ks], acc[mt][nt], 0, 0, 0);
        }
    }
    unsigned short* ob = (unsigned short*)e_out;
#pragma unroll
    for (int mt = 0; mt < 2; ++mt)
#pragma unroll
        for (int nt = 0; nt < 4; ++nt)
#pragma unroll
            for (int i = 0; i < 4; ++i) {
                long row = (long)blockIdx.x * 128 + (wv * 2 + mt) * 16 + q * 4 + i;
                if (row < (long)E)
                    ob[row * 64 + nt * 16 + lr] =
                        (unsigned short)f2bf(fmaxf(acc[mt][nt][i], 0.f));
            }
}

// ---------------- Aggregation: one wave per node; scalar (s_load) indices; online softmax --

__global__ __launch_bounds__(256) void k_agg(const float* __restrict__ h,
        const __hip_bfloat16* __restrict__ eperm, const int* __restrict__ sperm,
        const int* __restrict__ row_ptr, const float* __restrict__ t_ptr, int layer,
        float* __restrict__ y, int n) {
    int wid = blockIdx.x * 4 + (threadIdx.x >> 6);
    int lane = threadIdx.x & 63;
    if (wid >= n) return;
    wid = __builtin_amdgcn_readfirstlane(wid);   // wave-uniform -> scalar loads below
    float tval = t_ptr[layer];
    int beg = row_ptr[wid], end = row_ptr[wid + 1];
    float m = -INFINITY, den = 0.f, num = 0.f;
    int i = beg;
    if ((end - beg) & 1) {
        int s = sperm[i];
        float ev = __bfloat162float(eperm[(long)i * 64 + lane]);
        float hv = h[(long)s * 64 + lane];
        float msg = fmaxf(hv + ev, 0.f) + 1e-7f;
        m = msg * tval;
        den = 1.f;
        num = msg;
        ++i;
    }
    for (; i < end; i += 2) {
        int s0 = sperm[i];
        int s1 = sperm[i + 1];
        float ev0 = __bfloat162float(eperm[(long)i * 64 + lane]);
        float ev1 = __bfloat162float(eperm[(long)(i + 1) * 64 + lane]);
        float hv0 = h[(long)s0 * 64 + lane];
        float hv1 = h[(long)s1 * 64 + lane];
        float msg0 = fmaxf(hv0 + ev0, 0.f) + 1e-7f;
        float msg1 = fmaxf(hv1 + ev1, 0.f) + 1e-7f;
        float sv0 = msg0 * tval;
        float sv1 = msg1 * tval;
        float mn = fmaxf(fmaxf(m, sv0), sv1);   // v_max3
        float sc = __expf(m - mn);
        float w0 = __expf(sv0 - mn);
        float w1 = __expf(sv1 - mn);
        den = den * sc + w0 + w1;
        num = num * sc + w0 * msg0 + w1 * msg1;
        m = mn;
    }
    float agg = (end > beg) ? num / (den + 1e-16f) : 0.f;
    y[(long)wid * 64 + lane] = h[(long)wid * 64 + lane] + agg;
}

// ---------------- GEMM1 + fused BN partial stats ----------------

__global__ __launch_bounds__(256) void k_gemm1(const float* __restrict__ y,
        const float* __restrict__ W1, const float* __restrict__ b1,
        float* __restrict__ h1, float* __restrict__ part, int n) {
    __shared__ float sA[64][65];
    __shared__ float sW[64 * 128];
    __shared__ float sB[128];
    __shared__ float sS[8][128];
    __shared__ float sS2[8][128];
    int tid = threadIdx.x;
    int base = blockIdx.x * 64;
    for (int i = tid; i < 64 * 128 / 4; i += 256) ((float4*)sW)[i] = ((const float4*)W1)[i];
    if (tid < 128) sB[tid] = b1[tid];
    for (int i = tid; i < 64 * 64 / 4; i += 256) {
        int r = i / 16, c4 = i % 16;
        int row = base + r;
        float4 v = (row < n) ? ((const float4*)(y + (long)row * 64))[c4] : make_float4(0, 0, 0, 0);
        sA[r][c4 * 4 + 0] = v.x; sA[r][c4 * 4 + 1] = v.y;
        sA[r][c4 * 4 + 2] = v.z; sA[r][c4 * 4 + 3] = v.w;
    }
    __syncthreads();
    int rg = tid / 32;
    int r0 = rg * 8;
    int c0 = (tid % 32) * 4;
    float acc[8][4];
#pragma unroll
    for (int i = 0; i < 8; i++)
#pragma unroll
        for (int j = 0; j < 4; j++) acc[i][j] = sB[c0 + j];
    for (int k = 0; k < 64; k++) {
        float a[8], b[4];
#pragma unroll
        for (int i = 0; i < 8; i++) a[i] = sA[r0 + i][k];
#pragma unroll
        for (int j = 0; j < 4; j++) b[j] = sW[k * 128 + c0 + j];
#pragma unroll
        for (int i = 0; i < 8; i++)
#pragma unroll
            for (int j = 0; j < 4; j++) acc[i][j] += a[i] * b[j];
    }
    float ps[4] = {0, 0, 0, 0}, ps2[4] = {0, 0, 0, 0};
#pragma unroll
    for (int i = 0; i < 8; i++) {
        int row = base + r0 + i;
        if (row < n) {
            float4 v = make_float4(acc[i][0], acc[i][1], acc[i][2], acc[i][3]);
            *(float4*)(h1 + (long)row * 128 + c0) = v;
#pragma unroll
            for (int j = 0; j < 4; j++) { ps[j] += acc[i][j]; ps2[j] += acc[i][j] * acc[i][j]; }
        }
    }
#pragma unroll
    for (int j = 0; j < 4; j++) { sS[rg][c0 + j] = ps[j]; sS2[rg][c0 + j] = ps2[j]; }
    __syncthreads();
    if (tid < 128) {
        float s = 0.f, s2 = 0.f;
#pragma unroll
        for (int g = 0; g < 8; g++) { s += sS[g][tid]; s2 += sS2[g][tid]; }
        part[blockIdx.x * 256 + tid] = s;
        part[blockIdx.x * 256 + 128 + tid] = s2;
    }
}

// ---------------- BN reduce: tree stage (64 blocks) then finalize ----------------

__global__ __launch_bounds__(256) void k_bnred(const float* __restrict__ part,
                                               float* __restrict__ part2, int nblk) {
    int c = threadIdx.x;
    int b = blockIdx.x;
    float s = 0.f;
    for (int r = b; r < nblk; r += 64) s += part[r * 256 + c];
    part2[b * 256 + c] = s;
}

__global__ __launch_bounds__(1024) void k_bnfin(const float* __restrict__ part2,
                        const float* __restrict__ gamma, const float* __restrict__ beta,
                        float* __restrict__ scale, float* __restrict__ shift, float invN) {
    __shared__ float red[4][256];
    __shared__ float tot[256];
    int c = threadIdx.x & 255;
    int g = threadIdx.x >> 8;
    float s = 0.f;
#pragma unroll
    for (int r = 0; r < 16; ++r) s += part2[(g * 16 + r) * 256 + c];
    red[g][c] = s;
    __syncthreads();
    if (threadIdx.x < 256) tot[c] = red[0][c] + red[1][c] + red[2][c] + red[3][c];
    __syncthreads();
    if (threadIdx.x < 128) {
        int cc = threadIdx.x;
        float mu = tot[cc] * invN;
        float var = fmaxf(tot[128 + cc] * invN - mu * mu, 0.f);
        float sc = gamma[cc] * rsqrtf(var + 1e-5f);
        scale[cc] = sc;
        shift[cc] = beta[cc] - mu * sc;
    }
}

// ---------------- GEMM2: relu(bn(h1)) @ W2[128,64] + b2 -> hout[N,64] ----------------

__global__ __launch_bounds__(256) void k_gemm2(const float* __restrict__ h1,
        const float* __restrict__ scale, const float* __restrict__ shift,
        const float* __restrict__ W2, const float* __restrict__ b2,
        float* __restrict__ hout, int n, int dorelu) {
    __shared__ float sA[32][129];
    __shared__ float sW[128 * 64];
    __shared__ float sSc[128], sSh[128], sB[64];
    int tid = threadIdx.x;
    int base = blockIdx.x * 32;
    for (int i = tid; i < 128 * 64 / 4; i += 256) ((float4*)sW)[i] = ((const float4*)W2)[i];
    if (tid < 128) { sSc[tid] = scale[tid]; sSh[tid] = shift[tid]; }
    if (tid < 64) sB[tid] = b2[tid];
    __syncthreads();
    for (int i = tid; i < 32 * 128 / 4; i += 256) {
        int r = i / 32, c4 = i % 32;
        int row = base + r;
        float4 v = (row < n) ? ((const float4*)(h1 + (long)row * 128))[c4] : make_float4(0, 0, 0, 0);
        int c = c4 * 4;
        sA[r][c + 0] = fmaxf(v.x * sSc[c + 0] + sSh[c + 0], 0.f);
        sA[r][c + 1] = fmaxf(v.y * sSc[c + 1] + sSh[c + 1], 0.f);
        sA[r][c + 2] = fmaxf(v.z * sSc[c + 2] + sSh[c + 2], 0.f);
        sA[r][c + 3] = fmaxf(v.w * sSc[c + 3] + sSh[c + 3], 0.f);
    }
    __syncthreads();
    int r0 = (tid / 16) * 2;
    int c0 = (tid % 16) * 4;
    float acc[2][4];
#pragma unroll
    for (int i = 0; i < 2; i++)
#pragma unroll
        for (int j = 0; j < 4; j++) acc[i][j] = sB[c0 + j];
    for (int k = 0; k < 128; k++) {
        float a[2], b[4];
#pragma unroll
        for (int i = 0; i < 2; i++) a[i] = sA[r0 + i][k];
#pragma unroll
        for (int j = 0; j < 4; j++) b[j] = sW[k * 64 + c0 + j];
#pragma unroll
        for (int i = 0; i < 2; i++)
#pragma unroll
            for (int j = 0; j < 4; j++) acc[i][j] += a[i] * b[j];
    }
#pragma unroll
    for (int i = 0; i < 2; i++) {
        int row = base + r0 + i;
        if (row < n) {
            float4 v;
            v.x = dorelu ? fmaxf(acc[i][0], 0.f) : acc[i][0];
            v.y = dorelu ? fmaxf(acc[i][1], 0.f) : acc[i][1];
            v.z = dorelu ? fmaxf(acc[i][2], 0.f) : acc[i][2];
            v.w = dorelu ? fmaxf(acc[i][3], 0.f) : acc[i][3];
            *(float4*)(hout + (long)row * 64 + c0) = v;
        }
    }
}

// ---------------- Head: pool per graph + 2-layer MLP to scalar ----------------

__global__ __launch_bounds__(64) void k_head(const float* __restrict__ h,
        const int* __restrict__ gptr,
        const float* __restrict__ W1, const float* __restrict__ b1,
        const float* __restrict__ W2, const float* __restrict__ b2,
        float* __restrict__ out) {
    int g = blockIdx.x;
    int lane = threadIdx.x;
    int beg = gptr[g], end = gptr[g + 1];
    float s = 0.f;
    for (int r = beg; r < end; ++r) s += h[(long)r * 64 + lane];
    __shared__ float sg[64];
    sg[lane] = s;
    __syncthreads();
    float acc = b1[lane];
    for (int k = 0; k < 64; k++) acc += sg[k] * W1[k * 64 + lane];
    acc = fmaxf(acc, 0.f);
    float v = acc * W2[lane];
#pragma unroll
    for (int off = 32; off > 0; off >>= 1) v += __shfl_down(v, off, 64);
    if (lane == 0) out[g] = v + b2[0];
}

// ---------------- launch ----------------

extern "C" void kernel_launch(void* const* d_in, const int* in_sizes, int n_in,
                              void* d_out, int out_size, void* d_ws, size_t ws_size,
                              hipStream_t stream) {
    const float* x      = (const float*)d_in[0];
    const float* ea     = (const float*)d_in[1];
    const int*   ei     = (const int*)d_in[2];
    const int*   batch  = (const int*)d_in[3];
    const float* atomW1 = (const float*)d_in[4];
    const float* atomb1 = (const float*)d_in[5];
    const float* atomW2 = (const float*)d_in[6];
    const float* atomb2 = (const float*)d_in[7];
    const float* bondW1 = (const float*)d_in[8];
    const float* bondb1 = (const float*)d_in[9];
    const float* bondW2 = (const float*)d_in[10];
    const float* bondb2 = (const float*)d_in[11];
    const float* convT  = (const float*)d_in[12];
    const float* convW1 = (const float*)d_in[13];
    const float* convb1 = (const float*)d_in[14];
    const float* convG  = (const float*)d_in[15];
    const float* convBt = (const float*)d_in[16];
    const float* convW2 = (const float*)d_in[17];
    const float* convb2 = (const float*)d_in[18];
    const float* lin1W  = (const float*)d_in[19];
    const float* lin1b  = (const float*)d_in[20];
    const float* lin2W  = (const float*)d_in[21];
    const float* lin2b  = (const float*)d_in[22];
    float* out = (float*)d_out;

    const int N = in_sizes[0] / 32;
    const int E = in_sizes[1] / 16;
    const int G = out_size;
    const int Lconv = in_sizes[12];
    const int nchunk = (N + 1023) / 1024;
    const int nblk1 = (N + 63) / 64;

    size_t need = 0;
    auto count = [&](size_t bytes) { need += (bytes + 255) & ~(size_t)255; };
    count((size_t)E * 64 * 2);
    count((size_t)N * 64 * 4);
    count((size_t)N * 64 * 4);
    count((size_t)N * 128 * 4);
    count((size_t)E * 4);
    count((size_t)E * 4);
    count((size_t)(N + 1) * 4);
    count((size_t)N * 4);
    count((size_t)N * 4);
    count((size_t)(G + 1) * 4);
    count((size_t)nblk1 * 256 * 4);
    count((size_t)64 * 256 * 4);
    count(128 * 4); count(128 * 4);
    count((size_t)(nchunk + 1) * 4);
    count(4);
    count(1024 * 4);
    count(4096 * 2);
    if (ws_size < need) {
        hipMemsetAsync(d_out, 0, (size_t)out_size * 4, stream);
        return;
    }

    char* ws = (char*)d_ws;
    size_t off = 0;
    auto alloc = [&](size_t bytes) -> void* {
        void* p = ws + off;
        off += (bytes + 255) & ~(size_t)255;
        return p;
    };
    __hip_bfloat16* e_perm = (__hip_bfloat16*)alloc((size_t)E * 64 * 2);
    float* h_cur    = (float*)alloc((size_t)N * 64 * 4);
    float* y_buf    = (float*)alloc((size_t)N * 64 * 4);
    float* h1       = (float*)alloc((size_t)N * 128 * 4);
    int*   src_perm = (int*)alloc((size_t)E * 4);
    int*   eid_perm = (int*)alloc((size_t)E * 4);
    int*   row_ptr  = (int*)alloc((size_t)(N + 1) * 4);
    int*   counts   = (int*)alloc((size_t)N * 4);
    int*   fill     = (int*)alloc((size_t)N * 4);
    int*   gptr     = (int*)alloc((size_t)(G + 1) * 4);
    float* part     = (float*)alloc((size_t)nblk1 * 256 * 4);
    float* part2    = (float*)alloc((size_t)64 * 256 * 4);
    float* bnscale  = (float*)alloc(128 * 4);
    float* bnshift  = (float*)alloc(128 * 4);
    int*   csum     = (int*)alloc((size_t)(nchunk + 1) * 4);
    int*   totalp   = (int*)alloc(4);
    float* W1t      = (float*)alloc(1024 * 4);
    unsigned short* W2tb = (unsigned short*)alloc(4096 * 2);
    (void)n_in;

    hipMemsetAsync(counts, 0, (size_t)N * 4, stream);
    hipMemsetAsync(fill, 0, (size_t)N * 4, stream);

    const int* src = ei;
    const int* dst = ei + E;

    k_hist<<<(E + 255) / 256, 256, 0, stream>>>(dst, counts, E);
    k_scan1<<<nchunk, 1024, 0, stream>>>(counts, row_ptr, csum, N);
    k_scan2<<<1, 64, 0, stream>>>(csum, nchunk, totalp);
    k_scan3<<<(N + 255) / 256, 256, 0, stream>>>(row_ptr, csum, totalp, N);
    k_scatter<<<(E + 255) / 256, 256, 0, stream>>>(src, dst, row_ptr, fill, src_perm, eid_perm, E);
    k_gptr<<<(N + 256) / 256, 256, 0, stream>>>(batch, gptr, N, G);
    k_wt<<<16, 256, 0, stream>>>(bondW1, bondW2, W1t, W2tb);

    k_atom<<<(N + TM - 1) / TM, 256, 0, stream>>>(x, atomW1, atomb1, atomW2, atomb2, h_cur, N);
    k_bond<<<(E + 127) / 128, 256, 0, stream>>>(ea, eid_perm, W1t, bondb1, W2tb, bondb2,
                                                e_perm, E);

    for (int l = 0; l < Lconv; ++l) {
        k_agg<<<(N + 3) / 4, 256, 0, stream>>>(h_cur, e_perm, src_perm, row_ptr, convT, l, y_buf, N);
        k_gemm1<<<nblk1, 256, 0, stream>>>(y_buf, convW1 + (size_t)l * 64 * 128,
                                           convb1 + (size_t)l * 128, h1, part, N);
        k_bnred<<<64, 256, 0, stream>>>(part, part2, nblk1);
        k_bnfin<<<1, 1024, 0, stream>>>(part2, convG + (size_t)l * 128, convBt + (size_t)l * 128,
                                        bnscale, bnshift, 1.0f / (float)N);
        k_gemm2<<<(N + 31) / 32, 256, 0, stream>>>(h1, bnscale, bnshift,
                                                   convW2 + (size_t)l * 128 * 64,
                                                   convb2 + (size_t)l * 64, h_cur, N,
                                                   (l < Lconv - 1) ? 1 : 0);
    }

    k_head<<<G, 64, 0, stream>>>(h_cur, gptr, lin1W, lin1b, lin2W, lin2b, out);
}

// Round 9
// 657.148 us; speedup vs baseline: 1.4557x; 1.0195x over previous
//
#include <hip/hip_runtime.h>
#include <hip/hip_bf16.h>
#include <math.h>

typedef __attribute__((ext_vector_type(8))) short bf16x8;
typedef __attribute__((ext_vector_type(4))) float f32x4;

__device__ inline unsigned f2bf(float f) {
    union { __hip_bfloat16 h; unsigned short u; } cv;
    cv.h = __float2bfloat16(f);
    return (unsigned)cv.u;
}

// ---------------- CSR construction ----------------

__global__ void k_hist(const int* __restrict__ dst, int* __restrict__ counts, int E) {
    int e = blockIdx.x * blockDim.x + threadIdx.x;
    if (e < E) atomicAdd(&counts[dst[e]], 1);
}

__global__ void k_scan1(const int* __restrict__ counts, int* __restrict__ row_ptr,
                        int* __restrict__ csum, int n) {
    __shared__ int buf[1024];
    int tid = threadIdx.x;
    int base = blockIdx.x * 1024;
    int v = (base + tid < n) ? counts[base + tid] : 0;
    buf[tid] = v;
    __syncthreads();
    int inc = v;
    for (int off = 1; off < 1024; off <<= 1) {
        int add = (tid >= off) ? buf[tid - off] : 0;
        __syncthreads();
        inc += add;
        buf[tid] = inc;
        __syncthreads();
    }
    if (base + tid < n) row_ptr[base + tid] = inc - v;
    if (tid == 1023) csum[blockIdx.x] = inc;
}

__global__ void k_scan2(int* __restrict__ csum, int nc, int* __restrict__ total) {
    if (threadIdx.x == 0) {
        int run = 0;
        for (int i = 0; i < nc; ++i) { int c = csum[i]; csum[i] = run; run += c; }
        *total = run;
    }
}

__global__ void k_scan3(int* __restrict__ row_ptr, const int* __restrict__ csum,
                        const int* __restrict__ total, int n) {
    int i = blockIdx.x * blockDim.x + threadIdx.x;
    if (i < n) row_ptr[i] += csum[i >> 10];
    if (i == 0) row_ptr[n] = *total;
}

// packed scatter: one int2 {src, eid} per edge -> single 8B random write
__global__ void k_scatter(const int* __restrict__ src, const int* __restrict__ dst,
                          const int* __restrict__ row_ptr, int* __restrict__ fill,
                          int2* __restrict__ spe, int E) {
    int e = blockIdx.x * blockDim.x + threadIdx.x;
    if (e >= E) return;
    int d = dst[e];
    int pos = row_ptr[d] + atomicAdd(&fill[d], 1);
    spe[pos] = make_int2(src[e], e);
}

__global__ void k_gptr(const int* __restrict__ batch, int* __restrict__ gptr, int n, int G) {
    int i = blockIdx.x * blockDim.x + threadIdx.x;
    if (i > n) return;
    if (i == 0) {
        int b0 = batch[0];
        for (int g = 0; g <= b0; ++g) gptr[g] = 0;
    } else if (i == n) {
        int bl = batch[n - 1];
        for (int g = bl + 1; g <= G; ++g) gptr[g] = n;
    } else {
        int b = batch[i], pb = batch[i - 1];
        for (int g = pb + 1; g <= b; ++g) gptr[g] = i;
    }
}

// ---------------- weight transpose (tiny): W1t f32 [64][16], W2tb bf16 [64(N)][64(K)] ----

__global__ void k_wt(const float* __restrict__ W1, const float* __restrict__ W2,
                     float* __restrict__ W1t, unsigned short* __restrict__ W2tb) {
    int tid = blockIdx.x * blockDim.x + threadIdx.x;
    if (tid < 1024) {
        int j = tid / 16, k = tid % 16;
        W1t[j * 16 + k] = W1[k * 64 + j];
    }
    if (tid < 4096) {
        int j = tid / 64, k = tid % 64;
        W2tb[j * 64 + k] = (unsigned short)f2bf(W2[k * 64 + j]);
    }
}

// ---------------- Atom encoder: [M,32] -> relu -> [M,64] -> relu ----------------

#define TM 128
__global__ __launch_bounds__(256) void k_atom(const float* __restrict__ x,
        const float* __restrict__ W1, const float* __restrict__ b1,
        const float* __restrict__ W2, const float* __restrict__ b2,
        float* __restrict__ out, int M) {
    __shared__ float sU[TM * 65];
    __shared__ float sW1[32 * 64];
    __shared__ float sW2[64 * 64];
    __shared__ float sB1[64], sB2[64];
#define A_IN(r, c) sU[(r) * 33 + (c)]
#define A_T1(r, c) sU[(r) * 65 + (c)]
    int tid = threadIdx.x;
    int base = blockIdx.x * TM;
    for (int i = tid; i < 32 * 64 / 4; i += 256) ((float4*)sW1)[i] = ((const float4*)W1)[i];
    for (int i = tid; i < 64 * 64 / 4; i += 256) ((float4*)sW2)[i] = ((const float4*)W2)[i];
    if (tid < 64) { sB1[tid] = b1[tid]; sB2[tid] = b2[tid]; }
    for (int i = tid; i < TM * 32 / 4; i += 256) {
        int r = i / 8, c4 = i % 8;
        int row = base + r;
        float4 v = (row < M) ? ((const float4*)(x + (long)row * 32))[c4] : make_float4(0, 0, 0, 0);
        A_IN(r, c4 * 4 + 0) = v.x; A_IN(r, c4 * 4 + 1) = v.y;
        A_IN(r, c4 * 4 + 2) = v.z; A_IN(r, c4 * 4 + 3) = v.w;
    }
    __syncthreads();
    int r0 = (tid / 16) * 8;
    int c0 = (tid % 16) * 4;
    float acc[8][4];
#pragma unroll
    for (int i = 0; i < 8; i++)
#pragma unroll
        for (int j = 0; j < 4; j++) acc[i][j] = sB1[c0 + j];
    for (int k = 0; k < 32; k++) {
        float a[8], b[4];
#pragma unroll
        for (int i = 0; i < 8; i++) a[i] = A_IN(r0 + i, k);
#pragma unroll
        for (int j = 0; j < 4; j++) b[j] = sW1[k * 64 + c0 + j];
#pragma unroll
        for (int i = 0; i < 8; i++)
#pragma unroll
            for (int j = 0; j < 4; j++) acc[i][j] += a[i] * b[j];
    }
    __syncthreads();
#pragma unroll
    for (int i = 0; i < 8; i++)
#pragma unroll
        for (int j = 0; j < 4; j++) A_T1(r0 + i, c0 + j) = fmaxf(acc[i][j], 0.f);
    __syncthreads();
#pragma unroll
    for (int i = 0; i < 8; i++)
#pragma unroll
        for (int j = 0; j < 4; j++) acc[i][j] = sB2[c0 + j];
    for (int k = 0; k < 64; k++) {
        float a[8], b[4];
#pragma unroll
        for (int i = 0; i < 8; i++) a[i] = A_T1(r0 + i, k);
#pragma unroll
        for (int j = 0; j < 4; j++) b[j] = sW2[k * 64 + c0 + j];
#pragma unroll
        for (int i = 0; i < 8; i++)
#pragma unroll
            for (int j = 0; j < 4; j++) acc[i][j] += a[i] * b[j];
    }
#pragma unroll
    for (int i = 0; i < 8; i++) {
        int row = base + r0 + i;
        if (row < M) {
            float4 v = make_float4(fmaxf(acc[i][0], 0.f), fmaxf(acc[i][1], 0.f),
                                   fmaxf(acc[i][2], 0.f), fmaxf(acc[i][3], 0.f));
            *(float4*)(out + (long)row * 64 + c0) = v;
        }
    }
}

// ---------------- Bond encoder: layer1 f32 (wave-uniform s_load weights), layer2 MFMA ----

__global__ __launch_bounds__(256) void k_bond(const float* __restrict__ ea,
        const int2* __restrict__ spe,
        const float* __restrict__ W1t, const float* __restrict__ b1,
        const unsigned short* __restrict__ W2tb, const float* __restrict__ b2,
        __hip_bfloat16* __restrict__ e_out, int E) {
    __shared__ unsigned sT1[128 * 32];   // bf16[128][64], swizzled
    __shared__ unsigned sW2[64 * 32];    // bf16[64][64] (W2^T), swizzled
    int tid = threadIdx.x;

    for (int i = tid; i < 2048; i += 256) {
        int rw = i >> 5, cp = i & 31;
        sW2[rw * 32 + (cp ^ ((rw & 7) << 2))] = ((const unsigned*)W2tb)[i];
    }

    int ed = tid & 127;
    int h0 = __builtin_amdgcn_readfirstlane(tid >> 7);
    long gid = (long)blockIdx.x * 128 + ed;
    float in[16];
    if (gid < (long)E) {
        int src_e = spe[gid].y;   // eid
        const float4* er = (const float4*)(ea + (long)src_e * 16);
        float4 q0 = er[0], q1 = er[1], q2 = er[2], q3 = er[3];
        in[0] = q0.x; in[1] = q0.y; in[2] = q0.z; in[3] = q0.w;
        in[4] = q1.x; in[5] = q1.y; in[6] = q1.z; in[7] = q1.w;
        in[8] = q2.x; in[9] = q2.y; in[10] = q2.z; in[11] = q2.w;
        in[12] = q3.x; in[13] = q3.y; in[14] = q3.z; in[15] = q3.w;
    } else {
#pragma unroll
        for (int k = 0; k < 16; ++k) in[k] = 0.f;
    }

#pragma unroll
    for (int c = 0; c < 16; ++c) {
        float a0 = b1[h0 * 32 + 2 * c];
        float a1 = b1[h0 * 32 + 2 * c + 1];
#pragma unroll
        for (int k = 0; k < 16; ++k) {
            a0 = fmaf(in[k], W1t[(h0 * 32 + 2 * c) * 16 + k], a0);
            a1 = fmaf(in[k], W1t[(h0 * 32 + 2 * c + 1) * 16 + k], a1);
        }
        unsigned v = f2bf(fmaxf(a0, 0.f)) | (f2bf(fmaxf(a1, 0.f)) << 16);
        int cp = h0 * 16 + c;
        sT1[ed * 32 + (cp ^ ((ed & 7) << 2))] = v;
    }
    __syncthreads();

    int wv = tid >> 6, lane = tid & 63;
    int lr = lane & 15, q = lane >> 4;
    bf16x8 bf[4][2];
#pragma unroll
    for (int nt = 0; nt < 4; ++nt)
#pragma unroll
        for (int ks = 0; ks < 2; ++ks) {
            int rw = nt * 16 + lr;
            int u = rw * 32 + ((ks * 16 + q * 4) ^ ((rw & 7) << 2));
            bf[nt][ks] = *(const bf16x8*)&sW2[u];
        }
    f32x4 acc[2][4];
#pragma unroll
    for (int mt = 0; mt < 2; ++mt)
#pragma unroll
        for (int nt = 0; nt < 4; ++nt) {
            float bias = b2[nt * 16 + lr];
            f32x4 c0; c0[0] = bias; c0[1] = bias; c0[2] = bias; c0[3] = bias;
            acc[mt][nt] = c0;
        }
#pragma unroll
    for (int mt = 0; mt < 2; ++mt) {
        int rw = (wv * 2 + mt) * 16 + lr;
#pragma unroll
        for (int ks = 0; ks < 2; ++ks) {
            int u = rw * 32 + ((ks * 16 + q * 4) ^ ((rw & 7) << 2));
            bf16x8 af = *(const bf16x8*)&sT1[u];
#pragma unroll
            for (int nt = 0; nt < 4; ++nt)
                acc[mt][nt] = __builtin_amdgcn_mfma_f32_16x16x32_bf16(
                    af, bf[nt][ks], acc[mt][nt], 0, 0, 0);
        }
    }
    unsigned short* ob = (unsigned short*)e_out;
#pragma unroll
    for (int mt = 0; mt < 2; ++mt)
#pragma unroll
        for (int nt = 0; nt < 4; ++nt)
#pragma unroll
            for (int i = 0; i < 4; ++i) {
                long row = (long)blockIdx.x * 128 + (wv * 2 + mt) * 16 + q * 4 + i;
                if (row < (long)E)
                    ob[row * 64 + nt * 16 + lr] =
                        (unsigned short)f2bf(fmaxf(acc[mt][nt][i], 0.f));
            }
}

// ---------------- Aggregation: one wave per node; scalar indices; 4-wide online softmax ----

__global__ __launch_bounds__(256) void k_agg(const float* __restrict__ h,
        const __hip_bfloat16* __restrict__ eperm, const int2* __restrict__ spe,
        const int* __restrict__ row_ptr, const float* __restrict__ t_ptr, int layer,
        float* __restrict__ y, int n) {
    int wid = blockIdx.x * 4 + (threadIdx.x >> 6);
    int lane = threadIdx.x & 63;
    if (wid >= n) return;
    wid = __builtin_amdgcn_readfirstlane(wid);   // wave-uniform -> scalar loads
    float tval = t_ptr[layer];
    int beg = row_ptr[wid], end = row_ptr[wid + 1];
    float m = -INFINITY, den = 0.f, num = 0.f;
    int i = beg;
    int rem = (end - beg) & 3;
    for (int r = 0; r < rem; ++r, ++i) {
        int s = spe[i].x;
        float ev = __bfloat162float(eperm[(long)i * 64 + lane]);
        float hv = h[(long)s * 64 + lane];
        float msg = fmaxf(hv + ev, 0.f) + 1e-7f;
        float sv = msg * tval;
        float mn = fmaxf(m, sv);
        float sc = __expf(m - mn);
        float w = __expf(sv - mn);
        den = den * sc + w;
        num = num * sc + w * msg;
        m = mn;
    }
    for (; i < end; i += 4) {
        int s0 = spe[i].x, s1 = spe[i + 1].x, s2 = spe[i + 2].x, s3 = spe[i + 3].x;
        float ev0 = __bfloat162float(eperm[(long)i * 64 + lane]);
        float ev1 = __bfloat162float(eperm[(long)(i + 1) * 64 + lane]);
        float ev2 = __bfloat162float(eperm[(long)(i + 2) * 64 + lane]);
        float ev3 = __bfloat162float(eperm[(long)(i + 3) * 64 + lane]);
        float hv0 = h[(long)s0 * 64 + lane];
        float hv1 = h[(long)s1 * 64 + lane];
        float hv2 = h[(long)s2 * 64 + lane];
        float hv3 = h[(long)s3 * 64 + lane];
        float msg0 = fmaxf(hv0 + ev0, 0.f) + 1e-7f;
        float msg1 = fmaxf(hv1 + ev1, 0.f) + 1e-7f;
        float msg2 = fmaxf(hv2 + ev2, 0.f) + 1e-7f;
        float msg3 = fmaxf(hv3 + ev3, 0.f) + 1e-7f;
        float sv0 = msg0 * tval, sv1 = msg1 * tval;
        float sv2 = msg2 * tval, sv3 = msg3 * tval;
        float mn = fmaxf(fmaxf(fmaxf(m, sv0), fmaxf(sv1, sv2)), sv3);
        float sc = __expf(m - mn);
        float w0 = __expf(sv0 - mn);
        float w1 = __expf(sv1 - mn);
        float w2 = __expf(sv2 - mn);
        float w3 = __expf(sv3 - mn);
        den = den * sc + ((w0 + w1) + (w2 + w3));
        num = num * sc + ((w0 * msg0 + w1 * msg1) + (w2 * msg2 + w3 * msg3));
        m = mn;
    }
    float agg = (end > beg) ? num / (den + 1e-16f) : 0.f;
    y[(long)wid * 64 + lane] = h[(long)wid * 64 + lane] + agg;
}

// ---------------- GEMM1 + fused BN partial stats ----------------

__global__ __launch_bounds__(256) void k_gemm1(const float* __restrict__ y,
        const float* __restrict__ W1, const float* __restrict__ b1,
        float* __restrict__ h1, float* __restrict__ part, int n) {
    __shared__ float sA[64][65];
    __shared__ float sW[64 * 128];
    __shared__ float sB[128];
    __shared__ float sS[8][128];
    __shared__ float sS2[8][128];
    int tid = threadIdx.x;
    int base = blockIdx.x * 64;
    for (int i = tid; i < 64 * 128 / 4; i += 256) ((float4*)sW)[i] = ((const float4*)W1)[i];
    if (tid < 128) sB[tid] = b1[tid];
    for (int i = tid; i < 64 * 64 / 4; i += 256) {
        int r = i / 16, c4 = i % 16;
        int row = base + r;
        float4 v = (row < n) ? ((const float4*)(y + (long)row * 64))[c4] : make_float4(0, 0, 0, 0);
        sA[r][c4 * 4 + 0] = v.x; sA[r][c4 * 4 + 1] = v.y;
        sA[r][c4 * 4 + 2] = v.z; sA[r][c4 * 4 + 3] = v.w;
    }
    __syncthreads();
    int rg = tid / 32;
    int r0 = rg * 8;
    int c0 = (tid % 32) * 4;
    float acc[8][4];
#pragma unroll
    for (int i = 0; i < 8; i++)
#pragma unroll
        for (int j = 0; j < 4; j++) acc[i][j] = sB[c0 + j];
    for (int k = 0; k < 64; k++) {
        float a[8], b[4];
#pragma unroll
        for (int i = 0; i < 8; i++) a[i] = sA[r0 + i][k];
#pragma unroll
        for (int j = 0; j < 4; j++) b[j] = sW[k * 128 + c0 + j];
#pragma unroll
        for (int i = 0; i < 8; i++)
#pragma unroll
            for (int j = 0; j < 4; j++) acc[i][j] += a[i] * b[j];
    }
    float ps[4] = {0, 0, 0, 0}, ps2[4] = {0, 0, 0, 0};
#pragma unroll
    for (int i = 0; i < 8; i++) {
        int row = base + r0 + i;
        if (row < n) {
            float4 v = make_float4(acc[i][0], acc[i][1], acc[i][2], acc[i][3]);
            *(float4*)(h1 + (long)row * 128 + c0) = v;
#pragma unroll
            for (int j = 0; j < 4; j++) { ps[j] += acc[i][j]; ps2[j] += acc[i][j] * acc[i][j]; }
        }
    }
#pragma unroll
    for (int j = 0; j < 4; j++) { sS[rg][c0 + j] = ps[j]; sS2[rg][c0 + j] = ps2[j]; }
    __syncthreads();
    if (tid < 128) {
        float s = 0.f, s2 = 0.f;
#pragma unroll
        for (int g = 0; g < 8; g++) { s += sS[g][tid]; s2 += sS2[g][tid]; }
        part[blockIdx.x * 256 + tid] = s;
        part[blockIdx.x * 256 + 128 + tid] = s2;
    }
}

// ---------------- BN reduce: tree stage (64 blocks) then finalize ----------------

__global__ __launch_bounds__(256) void k_bnred(const float* __restrict__ part,
                                               float* __restrict__ part2, int nblk) {
    int c = threadIdx.x;
    int b = blockIdx.x;
    float s = 0.f;
    for (int r = b; r < nblk; r += 64) s += part[r * 256 + c];
    part2[b * 256 + c] = s;
}

__global__ __launch_bounds__(1024) void k_bnfin(const float* __restrict__ part2,
                        const float* __restrict__ gamma, const float* __restrict__ beta,
                        float* __restrict__ scale, float* __restrict__ shift, float invN) {
    __shared__ float red[4][256];
    __shared__ float tot[256];
    int c = threadIdx.x & 255;
    int g = threadIdx.x >> 8;
    float s = 0.f;
#pragma unroll
    for (int r = 0; r < 16; ++r) s += part2[(g * 16 + r) * 256 + c];
    red[g][c] = s;
    __syncthreads();
    if (threadIdx.x < 256) tot[c] = red[0][c] + red[1][c] + red[2][c] + red[3][c];
    __syncthreads();
    if (threadIdx.x < 128) {
        int cc = threadIdx.x;
        float mu = tot[cc] * invN;
        float var = fmaxf(tot[128 + cc] * invN - mu * mu, 0.f);
        float sc = gamma[cc] * rsqrtf(var + 1e-5f);
        scale[cc] = sc;
        shift[cc] = beta[cc] - mu * sc;
    }
}

// ---------------- GEMM2: relu(bn(h1)) @ W2[128,64] + b2 -> hout[N,64] ----------------

__global__ __launch_bounds__(256) void k_gemm2(const float* __restrict__ h1,
        const float* __restrict__ scale, const float* __restrict__ shift,
        const float* __restrict__ W2, const float* __restrict__ b2,
        float* __restrict__ hout, int n, int dorelu) {
    __shared__ float sA[32][129];
    __shared__ float sW[128 * 64];
    __shared__ float sSc[128], sSh[128], sB[64];
    int tid = threadIdx.x;
    int base = blockIdx.x * 32;
    for (int i = tid; i < 128 * 64 / 4; i += 256) ((float4*)sW)[i] = ((const float4*)W2)[i];
    if (tid < 128) { sSc[tid] = scale[tid]; sSh[tid] = shift[tid]; }
    if (tid < 64) sB[tid] = b2[tid];
    __syncthreads();
    for (int i = tid; i < 32 * 128 / 4; i += 256) {
        int r = i / 32, c4 = i % 32;
        int row = base + r;
        float4 v = (row < n) ? ((const float4*)(h1 + (long)row * 128))[c4] : make_float4(0, 0, 0, 0);
        int c = c4 * 4;
        sA[r][c + 0] = fmaxf(v.x * sSc[c + 0] + sSh[c + 0], 0.f);
        sA[r][c + 1] = fmaxf(v.y * sSc[c + 1] + sSh[c + 1], 0.f);
        sA[r][c + 2] = fmaxf(v.z * sSc[c + 2] + sSh[c + 2], 0.f);
        sA[r][c + 3] = fmaxf(v.w * sSc[c + 3] + sSh[c + 3], 0.f);
    }
    __syncthreads();
    int r0 = (tid / 16) * 2;
    int c0 = (tid % 16) * 4;
    float acc[2][4];
#pragma unroll
    for (int i = 0; i < 2; i++)
#pragma unroll
        for (int j = 0; j < 4; j++) acc[i][j] = sB[c0 + j];
    for (int k = 0; k < 128; k++) {
        float a[2], b[4];
#pragma unroll
        for (int i = 0; i < 2; i++) a[i] = sA[r0 + i][k];
#pragma unroll
        for (int j = 0; j < 4; j++) b[j] = sW[k * 64 + c0 + j];
#pragma unroll
        for (int i = 0; i < 2; i++)
#pragma unroll
            for (int j = 0; j < 4; j++) acc[i][j] += a[i] * b[j];
    }
#pragma unroll
    for (int i = 0; i < 2; i++) {
        int row = base + r0 + i;
        if (row < n) {
            float4 v;
            v.x = dorelu ? fmaxf(acc[i][0], 0.f) : acc[i][0];
            v.y = dorelu ? fmaxf(acc[i][1], 0.f) : acc[i][1];
            v.z = dorelu ? fmaxf(acc[i][2], 0.f) : acc[i][2];
            v.w = dorelu ? fmaxf(acc[i][3], 0.f) : acc[i][3];
            *(float4*)(hout + (long)row * 64 + c0) = v;
        }
    }
}

// ---------------- Head: pool per graph + 2-layer MLP to scalar ----------------

__global__ __launch_bounds__(64) void k_head(const float* __restrict__ h,
        const int* __restrict__ gptr,
        const float* __restrict__ W1, const float* __restrict__ b1,
        const float* __restrict__ W2, const float* __restrict__ b2,
        float* __restrict__ out) {
    int g = blockIdx.x;
    int lane = threadIdx.x;
    int beg = gptr[g], end = gptr[g + 1];
    float s = 0.f;
    for (int r = beg; r < end; ++r) s += h[(long)r * 64 + lane];
    __shared__ float sg[64];
    sg[lane] = s;
    __syncthreads();
    float acc = b1[lane];
    for (int k = 0; k < 64; k++) acc += sg[k] * W1[k * 64 + lane];
    acc = fmaxf(acc, 0.f);
    float v = acc * W2[lane];
#pragma unroll
    for (int off = 32; off > 0; off >>= 1) v += __shfl_down(v, off, 64);
    if (lane == 0) out[g] = v + b2[0];
}

// ---------------- launch ----------------

extern "C" void kernel_launch(void* const* d_in, const int* in_sizes, int n_in,
                              void* d_out, int out_size, void* d_ws, size_t ws_size,
                              hipStream_t stream) {
    const float* x      = (const float*)d_in[0];
    const float* ea     = (const float*)d_in[1];
    const int*   ei     = (const int*)d_in[2];
    const int*   batch  = (const int*)d_in[3];
    const float* atomW1 = (const float*)d_in[4];
    const float* atomb1 = (const float*)d_in[5];
    const float* atomW2 = (const float*)d_in[6];
    const float* atomb2 = (const float*)d_in[7];
    const float* bondW1 = (const float*)d_in[8];
    const float* bondb1 = (const float*)d_in[9];
    const float* bondW2 = (const float*)d_in[10];
    const float* bondb2 = (const float*)d_in[11];
    const float* convT  = (const float*)d_in[12];
    const float* convW1 = (const float*)d_in[13];
    const float* convb1 = (const float*)d_in[14];
    const float* convG  = (const float*)d_in[15];
    const float* convBt = (const float*)d_in[16];
    const float* convW2 = (const float*)d_in[17];
    const float* convb2 = (const float*)d_in[18];
    const float* lin1W  = (const float*)d_in[19];
    const float* lin1b  = (const float*)d_in[20];
    const float* lin2W  = (const float*)d_in[21];
    const float* lin2b  = (const float*)d_in[22];
    float* out = (float*)d_out;

    const int N = in_sizes[0] / 32;
    const int E = in_sizes[1] / 16;
    const int G = out_size;
    const int Lconv = in_sizes[12];
    const int nchunk = (N + 1023) / 1024;
    const int nblk1 = (N + 63) / 64;

    size_t need = 0;
    auto count = [&](size_t bytes) { need += (bytes + 255) & ~(size_t)255; };
    count((size_t)E * 64 * 2);
    count((size_t)N * 64 * 4);
    count((size_t)N * 64 * 4);
    count((size_t)N * 128 * 4);
    count((size_t)E * 8);                 // spe packed
    count((size_t)(N + 1) * 4);
    count((size_t)N * 4);
    count((size_t)N * 4);
    count((size_t)(G + 1) * 4);
    count((size_t)nblk1 * 256 * 4);
    count((size_t)64 * 256 * 4);
    count(128 * 4); count(128 * 4);
    count((size_t)(nchunk + 1) * 4);
    count(4);
    count(1024 * 4);
    count(4096 * 2);
    if (ws_size < need) {
        hipMemsetAsync(d_out, 0, (size_t)out_size * 4, stream);
        return;
    }

    char* ws = (char*)d_ws;
    size_t off = 0;
    auto alloc = [&](size_t bytes) -> void* {
        void* p = ws + off;
        off += (bytes + 255) & ~(size_t)255;
        return p;
    };
    __hip_bfloat16* e_perm = (__hip_bfloat16*)alloc((size_t)E * 64 * 2);
    float* h_cur    = (float*)alloc((size_t)N * 64 * 4);
    float* y_buf    = (float*)alloc((size_t)N * 64 * 4);
    float* h1       = (float*)alloc((size_t)N * 128 * 4);
    int2*  spe      = (int2*)alloc((size_t)E * 8);
    int*   row_ptr  = (int*)alloc((size_t)(N + 1) * 4);
    int*   counts   = (int*)alloc((size_t)N * 4);
    int*   fill     = (int*)alloc((size_t)N * 4);
    int*   gptr     = (int*)alloc((size_t)(G + 1) * 4);
    float* part     = (float*)alloc((size_t)nblk1 * 256 * 4);
    float* part2    = (float*)alloc((size_t)64 * 256 * 4);
    float* bnscale  = (float*)alloc(128 * 4);
    float* bnshift  = (float*)alloc(128 * 4);
    int*   csum     = (int*)alloc((size_t)(nchunk + 1) * 4);
    int*   totalp   = (int*)alloc(4);
    float* W1t      = (float*)alloc(1024 * 4);
    unsigned short* W2tb = (unsigned short*)alloc(4096 * 2);
    (void)n_in;

    hipMemsetAsync(counts, 0, (size_t)N * 4, stream);
    hipMemsetAsync(fill, 0, (size_t)N * 4, stream);

    const int* src = ei;
    const int* dst = ei + E;

    k_hist<<<(E + 255) / 256, 256, 0, stream>>>(dst, counts, E);
    k_scan1<<<nchunk, 1024, 0, stream>>>(counts, row_ptr, csum, N);
    k_scan2<<<1, 64, 0, stream>>>(csum, nchunk, totalp);
    k_scan3<<<(N + 255) / 256, 256, 0, stream>>>(row_ptr, csum, totalp, N);
    k_scatter<<<(E + 255) / 256, 256, 0, stream>>>(src, dst, row_ptr, fill, spe, E);
    k_gptr<<<(N + 256) / 256, 256, 0, stream>>>(batch, gptr, N, G);
    k_wt<<<16, 256, 0, stream>>>(bondW1, bondW2, W1t, W2tb);

    k_atom<<<(N + TM - 1) / TM, 256, 0, stream>>>(x, atomW1, atomb1, atomW2, atomb2, h_cur, N);
    k_bond<<<(E + 127) / 128, 256, 0, stream>>>(ea, spe, W1t, bondb1, W2tb, bondb2, e_perm, E);

    for (int l = 0; l < Lconv; ++l) {
        k_agg<<<(N + 3) / 4, 256, 0, stream>>>(h_cur, e_perm, spe, row_ptr, convT, l, y_buf, N);
        k_gemm1<<<nblk1, 256, 0, stream>>>(y_buf, convW1 + (size_t)l * 64 * 128,
                                           convb1 + (size_t)l * 128, h1, part, N);
        k_bnred<<<64, 256, 0, stream>>>(part, part2, nblk1);
        k_bnfin<<<1, 1024, 0, stream>>>(part2, convG + (size_t)l * 128, convBt + (size_t)l * 128,
                                        bnscale, bnshift, 1.0f / (float)N);
        k_gemm2<<<(N + 31) / 32, 256, 0, stream>>>(h1, bnscale, bnshift,
                                                   convW2 + (size_t)l * 128 * 64,
                                                   convb2 + (size_t)l * 64, h_cur, N,
                                                   (l < Lconv - 1) ? 1 : 0);
    }

    k_head<<<G, 64, 0, stream>>>(h_cur, gptr, lin1W, lin1b, lin2W, lin2b, out);
}

// Round 10
// 651.133 us; speedup vs baseline: 1.4691x; 1.0092x over previous
//
#include <hip/hip_runtime.h>
#include <hip/hip_bf16.h>
#include <math.h>

typedef __attribute__((ext_vector_type(8))) short bf16x8;
typedef __attribute__((ext_vector_type(4))) float f32x4;

__device__ inline unsigned f2bf(float f) {
    union { __hip_bfloat16 h; unsigned short u; } cv;
    cv.h = __float2bfloat16(f);
    return (unsigned)cv.u;
}

// ---------------- CSR construction ----------------

__global__ void k_hist(const int* __restrict__ dst, int* __restrict__ counts, int E) {
    int e = blockIdx.x * blockDim.x + threadIdx.x;
    if (e < E) atomicAdd(&counts[dst[e]], 1);
}

__global__ void k_scan1(const int* __restrict__ counts, int* __restrict__ row_ptr,
                        int* __restrict__ csum, int n) {
    __shared__ int buf[1024];
    int tid = threadIdx.x;
    int base = blockIdx.x * 1024;
    int v = (base + tid < n) ? counts[base + tid] : 0;
    buf[tid] = v;
    __syncthreads();
    int inc = v;
    for (int off = 1; off < 1024; off <<= 1) {
        int add = (tid >= off) ? buf[tid - off] : 0;
        __syncthreads();
        inc += add;
        buf[tid] = inc;
        __syncthreads();
    }
    if (base + tid < n) row_ptr[base + tid] = inc - v;
    if (tid == 1023) csum[blockIdx.x] = inc;
}

__global__ void k_scan2(int* __restrict__ csum, int nc, int* __restrict__ total) {
    if (threadIdx.x == 0) {
        int run = 0;
        for (int i = 0; i < nc; ++i) { int c = csum[i]; csum[i] = run; run += c; }
        *total = run;
    }
}

__global__ void k_scan3(int* __restrict__ row_ptr, const int* __restrict__ csum,
                        const int* __restrict__ total, int n) {
    int i = blockIdx.x * blockDim.x + threadIdx.x;
    if (i < n) row_ptr[i] += csum[i >> 10];
    if (i == 0) row_ptr[n] = *total;
}

// XCD-sliced scatter: slice s = blockIdx&7 handles dst in [s*NS, (s+1)*NS) of
// chunk blockIdx>>3. Slice regions of spe are contiguous (row_ptr monotone),
// so each region is written by (mostly) one XCD -> no cross-XCD line sharing.
#define ECH 4096
__global__ __launch_bounds__(256) void k_scatter(const int* __restrict__ src,
                          const int* __restrict__ dst,
                          const int* __restrict__ row_ptr, int* __restrict__ fill,
                          int2* __restrict__ spe, int E, int NS) {
    int bs = blockIdx.x & 7;
    int chunk = blockIdx.x >> 3;
    int base = chunk * ECH;
    int lo = bs * NS, hi = lo + NS;
#pragma unroll 1
    for (int j = 0; j < ECH / 256; ++j) {
        int e = base + j * 256 + threadIdx.x;
        if (e < E) {
            int d = dst[e];
            if (d >= lo && d < hi) {
                int pos = row_ptr[d] + atomicAdd(&fill[d], 1);
                spe[pos] = make_int2(src[e], e);
            }
        }
    }
}

__global__ void k_gptr(const int* __restrict__ batch, int* __restrict__ gptr, int n, int G) {
    int i = blockIdx.x * blockDim.x + threadIdx.x;
    if (i > n) return;
    if (i == 0) {
        int b0 = batch[0];
        for (int g = 0; g <= b0; ++g) gptr[g] = 0;
    } else if (i == n) {
        int bl = batch[n - 1];
        for (int g = bl + 1; g <= G; ++g) gptr[g] = n;
    } else {
        int b = batch[i], pb = batch[i - 1];
        for (int g = pb + 1; g <= b; ++g) gptr[g] = i;
    }
}

// ---------------- weight transpose (tiny): W1t f32 [64][16], W2tb bf16 [64(N)][64(K)] ----

__global__ void k_wt(const float* __restrict__ W1, const float* __restrict__ W2,
                     float* __restrict__ W1t, unsigned short* __restrict__ W2tb) {
    int tid = blockIdx.x * blockDim.x + threadIdx.x;
    if (tid < 1024) {
        int j = tid / 16, k = tid % 16;
        W1t[j * 16 + k] = W1[k * 64 + j];
    }
    if (tid < 4096) {
        int j = tid / 64, k = tid % 64;
        W2tb[j * 64 + k] = (unsigned short)f2bf(W2[k * 64 + j]);
    }
}

// ---------------- Atom encoder: [M,32] -> relu -> [M,64] -> relu ----------------

#define TM 128
__global__ __launch_bounds__(256) void k_atom(const float* __restrict__ x,
        const float* __restrict__ W1, const float* __restrict__ b1,
        const float* __restrict__ W2, const float* __restrict__ b2,
        float* __restrict__ out, int M) {
    __shared__ float sU[TM * 65];
    __shared__ float sW1[32 * 64];
    __shared__ float sW2[64 * 64];
    __shared__ float sB1[64], sB2[64];
#define A_IN(r, c) sU[(r) * 33 + (c)]
#define A_T1(r, c) sU[(r) * 65 + (c)]
    int tid = threadIdx.x;
    int base = blockIdx.x * TM;
    for (int i = tid; i < 32 * 64 / 4; i += 256) ((float4*)sW1)[i] = ((const float4*)W1)[i];
    for (int i = tid; i < 64 * 64 / 4; i += 256) ((float4*)sW2)[i] = ((const float4*)W2)[i];
    if (tid < 64) { sB1[tid] = b1[tid]; sB2[tid] = b2[tid]; }
    for (int i = tid; i < TM * 32 / 4; i += 256) {
        int r = i / 8, c4 = i % 8;
        int row = base + r;
        float4 v = (row < M) ? ((const float4*)(x + (long)row * 32))[c4] : make_float4(0, 0, 0, 0);
        A_IN(r, c4 * 4 + 0) = v.x; A_IN(r, c4 * 4 + 1) = v.y;
        A_IN(r, c4 * 4 + 2) = v.z; A_IN(r, c4 * 4 + 3) = v.w;
    }
    __syncthreads();
    int r0 = (tid / 16) * 8;
    int c0 = (tid % 16) * 4;
    float acc[8][4];
#pragma unroll
    for (int i = 0; i < 8; i++)
#pragma unroll
        for (int j = 0; j < 4; j++) acc[i][j] = sB1[c0 + j];
    for (int k = 0; k < 32; k++) {
        float a[8], b[4];
#pragma unroll
        for (int i = 0; i < 8; i++) a[i] = A_IN(r0 + i, k);
#pragma unroll
        for (int j = 0; j < 4; j++) b[j] = sW1[k * 64 + c0 + j];
#pragma unroll
        for (int i = 0; i < 8; i++)
#pragma unroll
            for (int j = 0; j < 4; j++) acc[i][j] += a[i] * b[j];
    }
    __syncthreads();
#pragma unroll
    for (int i = 0; i < 8; i++)
#pragma unroll
        for (int j = 0; j < 4; j++) A_T1(r0 + i, c0 + j) = fmaxf(acc[i][j], 0.f);
    __syncthreads();
#pragma unroll
    for (int i = 0; i < 8; i++)
#pragma unroll
        for (int j = 0; j < 4; j++) acc[i][j] = sB2[c0 + j];
    for (int k = 0; k < 64; k++) {
        float a[8], b[4];
#pragma unroll
        for (int i = 0; i < 8; i++) a[i] = A_T1(r0 + i, k);
#pragma unroll
        for (int j = 0; j < 4; j++) b[j] = sW2[k * 64 + c0 + j];
#pragma unroll
        for (int i = 0; i < 8; i++)
#pragma unroll
            for (int j = 0; j < 4; j++) acc[i][j] += a[i] * b[j];
    }
#pragma unroll
    for (int i = 0; i < 8; i++) {
        int row = base + r0 + i;
        if (row < M) {
            float4 v = make_float4(fmaxf(acc[i][0], 0.f), fmaxf(acc[i][1], 0.f),
                                   fmaxf(acc[i][2], 0.f), fmaxf(acc[i][3], 0.f));
            *(float4*)(out + (long)row * 64 + c0) = v;
        }
    }
}

// ---------------- Bond encoder: layer1 f32 (wave-uniform s_load weights), layer2 MFMA ----

__global__ __launch_bounds__(256) void k_bond(const float* __restrict__ ea,
        const int2* __restrict__ spe,
        const float* __restrict__ W1t, const float* __restrict__ b1,
        const unsigned short* __restrict__ W2tb, const float* __restrict__ b2,
        __hip_bfloat16* __restrict__ e_out, int E) {
    __shared__ unsigned sT1[128 * 32];   // bf16[128][64], swizzled
    __shared__ unsigned sW2[64 * 32];    // bf16[64][64] (W2^T), swizzled
    int tid = threadIdx.x;

    for (int i = tid; i < 2048; i += 256) {
        int rw = i >> 5, cp = i & 31;
        sW2[rw * 32 + (cp ^ ((rw & 7) << 2))] = ((const unsigned*)W2tb)[i];
    }

    int ed = tid & 127;
    int h0 = __builtin_amdgcn_readfirstlane(tid >> 7);
    long gid = (long)blockIdx.x * 128 + ed;
    float in[16];
    if (gid < (long)E) {
        int src_e = spe[gid].y;   // eid
        const float4* er = (const float4*)(ea + (long)src_e * 16);
        float4 q0 = er[0], q1 = er[1], q2 = er[2], q3 = er[3];
        in[0] = q0.x; in[1] = q0.y; in[2] = q0.z; in[3] = q0.w;
        in[4] = q1.x; in[5] = q1.y; in[6] = q1.z; in[7] = q1.w;
        in[8] = q2.x; in[9] = q2.y; in[10] = q2.z; in[11] = q2.w;
        in[12] = q3.x; in[13] = q3.y; in[14] = q3.z; in[15] = q3.w;
    } else {
#pragma unroll
        for (int k = 0; k < 16; ++k) in[k] = 0.f;
    }

#pragma unroll
    for (int c = 0; c < 16; ++c) {
        float a0 = b1[h0 * 32 + 2 * c];
        float a1 = b1[h0 * 32 + 2 * c + 1];
#pragma unroll
        for (int k = 0; k < 16; ++k) {
            a0 = fmaf(in[k], W1t[(h0 * 32 + 2 * c) * 16 + k], a0);
            a1 = fmaf(in[k], W1t[(h0 * 32 + 2 * c + 1) * 16 + k], a1);
        }
        unsigned v = f2bf(fmaxf(a0, 0.f)) | (f2bf(fmaxf(a1, 0.f)) << 16);
        int cp = h0 * 16 + c;
        sT1[ed * 32 + (cp ^ ((ed & 7) << 2))] = v;
    }
    __syncthreads();

    int wv = tid >> 6, lane = tid & 63;
    int lr = lane & 15, q = lane >> 4;
    bf16x8 bf[4][2];
#pragma unroll
    for (int nt = 0; nt < 4; ++nt)
#pragma unroll
        for (int ks = 0; ks < 2; ++ks) {
            int rw = nt * 16 + lr;
            int u = rw * 32 + ((ks * 16 + q * 4) ^ ((rw & 7) << 2));
            bf[nt][ks] = *(const bf16x8*)&sW2[u];
        }
    f32x4 acc[2][4];
#pragma unroll
    for (int mt = 0; mt < 2; ++mt)
#pragma unroll
        for (int nt = 0; nt < 4; ++nt) {
            float bias = b2[nt * 16 + lr];
            f32x4 c0; c0[0] = bias; c0[1] = bias; c0[2] = bias; c0[3] = bias;
            acc[mt][nt] = c0;
        }
#pragma unroll
    for (int mt = 0; mt < 2; ++mt) {
        int rw = (wv * 2 + mt) * 16 + lr;
#pragma unroll
        for (int ks = 0; ks < 2; ++ks) {
            int u = rw * 32 + ((ks * 16 + q * 4) ^ ((rw & 7) << 2));
            bf16x8 af = *(const bf16x8*)&sT1[u];
#pragma unroll
            for (int nt = 0; nt < 4; ++nt)
                acc[mt][nt] = __builtin_amdgcn_mfma_f32_16x16x32_bf16(
                    af, bf[nt][ks], acc[mt][nt], 0, 0, 0);
        }
    }
    unsigned short* ob = (unsigned short*)e_out;
#pragma unroll
    for (int mt = 0; mt < 2; ++mt)
#pragma unroll
        for (int nt = 0; nt < 4; ++nt)
#pragma unroll
            for (int i = 0; i < 4; ++i) {
                long row = (long)blockIdx.x * 128 + (wv * 2 + mt) * 16 + q * 4 + i;
                if (row < (long)E)
                    ob[row * 64 + nt * 16 + lr] =
                        (unsigned short)f2bf(fmaxf(acc[mt][nt][i], 0.f));
            }
}

// ---------------- Aggregation: one wave per node; scalar indices; 4-wide online softmax ----

__global__ __launch_bounds__(256) void k_agg(const float* __restrict__ h,
        const __hip_bfloat16* __restrict__ eperm, const int2* __restrict__ spe,
        const int* __restrict__ row_ptr, const float* __restrict__ t_ptr, int layer,
        float* __restrict__ y, int n) {
    int wid = blockIdx.x * 4 + (threadIdx.x >> 6);
    int lane = threadIdx.x & 63;
    if (wid >= n) return;
    wid = __builtin_amdgcn_readfirstlane(wid);   // wave-uniform -> scalar loads
    float tval = t_ptr[layer];
    int beg = row_ptr[wid], end = row_ptr[wid + 1];
    float m = -INFINITY, den = 0.f, num = 0.f;
    int i = beg;
    int rem = (end - beg) & 3;
    for (int r = 0; r < rem; ++r, ++i) {
        int s = spe[i].x;
        float ev = __bfloat162float(eperm[(long)i * 64 + lane]);
        float hv = h[(long)s * 64 + lane];
        float msg = fmaxf(hv + ev, 0.f) + 1e-7f;
        float sv = msg * tval;
        float mn = fmaxf(m, sv);
        float sc = __expf(m - mn);
        float w = __expf(sv - mn);
        den = den * sc + w;
        num = num * sc + w * msg;
        m = mn;
    }
    for (; i < end; i += 4) {
        int s0 = spe[i].x, s1 = spe[i + 1].x, s2 = spe[i + 2].x, s3 = spe[i + 3].x;
        float ev0 = __bfloat162float(eperm[(long)i * 64 + lane]);
        float ev1 = __bfloat162float(eperm[(long)(i + 1) * 64 + lane]);
        float ev2 = __bfloat162float(eperm[(long)(i + 2) * 64 + lane]);
        float ev3 = __bfloat162float(eperm[(long)(i + 3) * 64 + lane]);
        float hv0 = h[(long)s0 * 64 + lane];
        float hv1 = h[(long)s1 * 64 + lane];
        float hv2 = h[(long)s2 * 64 + lane];
        float hv3 = h[(long)s3 * 64 + lane];
        float msg0 = fmaxf(hv0 + ev0, 0.f) + 1e-7f;
        float msg1 = fmaxf(hv1 + ev1, 0.f) + 1e-7f;
        float msg2 = fmaxf(hv2 + ev2, 0.f) + 1e-7f;
        float msg3 = fmaxf(hv3 + ev3, 0.f) + 1e-7f;
        float sv0 = msg0 * tval, sv1 = msg1 * tval;
        float sv2 = msg2 * tval, sv3 = msg3 * tval;
        float mn = fmaxf(fmaxf(fmaxf(m, sv0), fmaxf(sv1, sv2)), sv3);
        float sc = __expf(m - mn);
        float w0 = __expf(sv0 - mn);
        float w1 = __expf(sv1 - mn);
        float w2 = __expf(sv2 - mn);
        float w3 = __expf(sv3 - mn);
        den = den * sc + ((w0 + w1) + (w2 + w3));
        num = num * sc + ((w0 * msg0 + w1 * msg1) + (w2 * msg2 + w3 * msg3));
        m = mn;
    }
    float agg = (end > beg) ? num / (den + 1e-16f) : 0.f;
    y[(long)wid * 64 + lane] = h[(long)wid * 64 + lane] + agg;
}

// ---------------- GEMM1 + fused BN partial stats ----------------

__global__ __launch_bounds__(256) void k_gemm1(const float* __restrict__ y,
        const float* __restrict__ W1, const float* __restrict__ b1,
        float* __restrict__ h1, float* __restrict__ part, int n) {
    __shared__ float sA[64][65];
    __shared__ float sW[64 * 128];
    __shared__ float sB[128];
    __shared__ float sS[8][128];
    __shared__ float sS2[8][128];
    int tid = threadIdx.x;
    int base = blockIdx.x * 64;
    for (int i = tid; i < 64 * 128 / 4; i += 256) ((float4*)sW)[i] = ((const float4*)W1)[i];
    if (tid < 128) sB[tid] = b1[tid];
    for (int i = tid; i < 64 * 64 / 4; i += 256) {
        int r = i / 16, c4 = i % 16;
        int row = base + r;
        float4 v = (row < n) ? ((const float4*)(y + (long)row * 64))[c4] : make_float4(0, 0, 0, 0);
        sA[r][c4 * 4 + 0] = v.x; sA[r][c4 * 4 + 1] = v.y;
        sA[r][c4 * 4 + 2] = v.z; sA[r][c4 * 4 + 3] = v.w;
    }
    __syncthreads();
    int rg = tid / 32;
    int r0 = rg * 8;
    int c0 = (tid % 32) * 4;
    float acc[8][4];
#pragma unroll
    for (int i = 0; i < 8; i++)
#pragma unroll
        for (int j = 0; j < 4; j++) acc[i][j] = sB[c0 + j];
    for (int k = 0; k < 64; k++) {
        float a[8], b[4];
#pragma unroll
        for (int i = 0; i < 8; i++) a[i] = sA[r0 + i][k];
#pragma unroll
        for (int j = 0; j < 4; j++) b[j] = sW[k * 128 + c0 + j];
#pragma unroll
        for (int i = 0; i < 8; i++)
#pragma unroll
            for (int j = 0; j < 4; j++) acc[i][j] += a[i] * b[j];
    }
    float ps[4] = {0, 0, 0, 0}, ps2[4] = {0, 0, 0, 0};
#pragma unroll
    for (int i = 0; i < 8; i++) {
        int row = base + r0 + i;
        if (row < n) {
            float4 v = make_float4(acc[i][0], acc[i][1], acc[i][2], acc[i][3]);
            *(float4*)(h1 + (long)row * 128 + c0) = v;
#pragma unroll
            for (int j = 0; j < 4; j++) { ps[j] += acc[i][j]; ps2[j] += acc[i][j] * acc[i][j]; }
        }
    }
#pragma unroll
    for (int j = 0; j < 4; j++) { sS[rg][c0 + j] = ps[j]; sS2[rg][c0 + j] = ps2[j]; }
    __syncthreads();
    if (tid < 128) {
        float s = 0.f, s2 = 0.f;
#pragma unroll
        for (int g = 0; g < 8; g++) { s += sS[g][tid]; s2 += sS2[g][tid]; }
        part[blockIdx.x * 256 + tid] = s;
        part[blockIdx.x * 256 + 128 + tid] = s2;
    }
}

// ---------------- BN reduce: tree stage (64 blocks) then finalize ----------------

__global__ __launch_bounds__(256) void k_bnred(const float* __restrict__ part,
                                               float* __restrict__ part2, int nblk) {
    int c = threadIdx.x;
    int b = blockIdx.x;
    float s = 0.f;
    for (int r = b; r < nblk; r += 64) s += part[r * 256 + c];
    part2[b * 256 + c] = s;
}

__global__ __launch_bounds__(1024) void k_bnfin(const float* __restrict__ part2,
                        const float* __restrict__ gamma, const float* __restrict__ beta,
                        float* __restrict__ scale, float* __restrict__ shift, float invN) {
    __shared__ float red[4][256];
    __shared__ float tot[256];
    int c = threadIdx.x & 255;
    int g = threadIdx.x >> 8;
    float s = 0.f;
#pragma unroll
    for (int r = 0; r < 16; ++r) s += part2[(g * 16 + r) * 256 + c];
    red[g][c] = s;
    __syncthreads();
    if (threadIdx.x < 256) tot[c] = red[0][c] + red[1][c] + red[2][c] + red[3][c];
    __syncthreads();
    if (threadIdx.x < 128) {
        int cc = threadIdx.x;
        float mu = tot[cc] * invN;
        float var = fmaxf(tot[128 + cc] * invN - mu * mu, 0.f);
        float sc = gamma[cc] * rsqrtf(var + 1e-5f);
        scale[cc] = sc;
        shift[cc] = beta[cc] - mu * sc;
    }
}

// ---------------- GEMM2: relu(bn(h1)) @ W2[128,64] + b2 -> hout[N,64] ----------------

__global__ __launch_bounds__(256) void k_gemm2(const float* __restrict__ h1,
        const float* __restrict__ scale, const float* __restrict__ shift,
        const float* __restrict__ W2, const float* __restrict__ b2,
        float* __restrict__ hout, int n, int dorelu) {
    __shared__ float sA[32][129];
    __shared__ float sW[128 * 64];
    __shared__ float sSc[128], sSh[128], sB[64];
    int tid = threadIdx.x;
    int base = blockIdx.x * 32;
    for (int i = tid; i < 128 * 64 / 4; i += 256) ((float4*)sW)[i] = ((const float4*)W2)[i];
    if (tid < 128) { sSc[tid] = scale[tid]; sSh[tid] = shift[tid]; }
    if (tid < 64) sB[tid] = b2[tid];
    __syncthreads();
    for (int i = tid; i < 32 * 128 / 4; i += 256) {
        int r = i / 32, c4 = i % 32;
        int row = base + r;
        float4 v = (row < n) ? ((const float4*)(h1 + (long)row * 128))[c4] : make_float4(0, 0, 0, 0);
        int c = c4 * 4;
        sA[r][c + 0] = fmaxf(v.x * sSc[c + 0] + sSh[c + 0], 0.f);
        sA[r][c + 1] = fmaxf(v.y * sSc[c + 1] + sSh[c + 1], 0.f);
        sA[r][c + 2] = fmaxf(v.z * sSc[c + 2] + sSh[c + 2], 0.f);
        sA[r][c + 3] = fmaxf(v.w * sSc[c + 3] + sSh[c + 3], 0.f);
    }
    __syncthreads();
    int r0 = (tid / 16) * 2;
    int c0 = (tid % 16) * 4;
    float acc[2][4];
#pragma unroll
    for (int i = 0; i < 2; i++)
#pragma unroll
        for (int j = 0; j < 4; j++) acc[i][j] = sB[c0 + j];
    for (int k = 0; k < 128; k++) {
        float a[2], b[4];
#pragma unroll
        for (int i = 0; i < 2; i++) a[i] = sA[r0 + i][k];
#pragma unroll
        for (int j = 0; j < 4; j++) b[j] = sW[k * 64 + c0 + j];
#pragma unroll
        for (int i = 0; i < 2; i++)
#pragma unroll
            for (int j = 0; j < 4; j++) acc[i][j] += a[i] * b[j];
    }
#pragma unroll
    for (int i = 0; i < 2; i++) {
        int row = base + r0 + i;
        if (row < n) {
            float4 v;
            v.x = dorelu ? fmaxf(acc[i][0], 0.f) : acc[i][0];
            v.y = dorelu ? fmaxf(acc[i][1], 0.f) : acc[i][1];
            v.z = dorelu ? fmaxf(acc[i][2], 0.f) : acc[i][2];
            v.w = dorelu ? fmaxf(acc[i][3], 0.f) : acc[i][3];
            *(float4*)(hout + (long)row * 64 + c0) = v;
        }
    }
}

// ---------------- Head: pool per graph + 2-layer MLP to scalar ----------------

__global__ __launch_bounds__(64) void k_head(const float* __restrict__ h,
        const int* __restrict__ gptr,
        const float* __restrict__ W1, const float* __restrict__ b1,
        const float* __restrict__ W2, const float* __restrict__ b2,
        float* __restrict__ out) {
    int g = blockIdx.x;
    int lane = threadIdx.x;
    int beg = gptr[g], end = gptr[g + 1];
    float s = 0.f;
    for (int r = beg; r < end; ++r) s += h[(long)r * 64 + lane];
    __shared__ float sg[64];
    sg[lane] = s;
    __syncthreads();
    float acc = b1[lane];
    for (int k = 0; k < 64; k++) acc += sg[k] * W1[k * 64 + lane];
    acc = fmaxf(acc, 0.f);
    float v = acc * W2[lane];
#pragma unroll
    for (int off = 32; off > 0; off >>= 1) v += __shfl_down(v, off, 64);
    if (lane == 0) out[g] = v + b2[0];
}

// ---------------- launch ----------------

extern "C" void kernel_launch(void* const* d_in, const int* in_sizes, int n_in,
                              void* d_out, int out_size, void* d_ws, size_t ws_size,
                              hipStream_t stream) {
    const float* x      = (const float*)d_in[0];
    const float* ea     = (const float*)d_in[1];
    const int*   ei     = (const int*)d_in[2];
    const int*   batch  = (const int*)d_in[3];
    const float* atomW1 = (const float*)d_in[4];
    const float* atomb1 = (const float*)d_in[5];
    const float* atomW2 = (const float*)d_in[6];
    const float* atomb2 = (const float*)d_in[7];
    const float* bondW1 = (const float*)d_in[8];
    const float* bondb1 = (const float*)d_in[9];
    const float* bondW2 = (const float*)d_in[10];
    const float* bondb2 = (const float*)d_in[11];
    const float* convT  = (const float*)d_in[12];
    const float* convW1 = (const float*)d_in[13];
    const float* convb1 = (const float*)d_in[14];
    const float* convG  = (const float*)d_in[15];
    const float* convBt = (const float*)d_in[16];
    const float* convW2 = (const float*)d_in[17];
    const float* convb2 = (const float*)d_in[18];
    const float* lin1W  = (const float*)d_in[19];
    const float* lin1b  = (const float*)d_in[20];
    const float* lin2W  = (const float*)d_in[21];
    const float* lin2b  = (const float*)d_in[22];
    float* out = (float*)d_out;

    const int N = in_sizes[0] / 32;
    const int E = in_sizes[1] / 16;
    const int G = out_size;
    const int Lconv = in_sizes[12];
    const int nchunk = (N + 1023) / 1024;
    const int nblk1 = (N + 63) / 64;
    const int NS = (N + 7) / 8;                    // nodes per dst-slice
    const int nchE = (E + ECH - 1) / ECH;          // edge chunks for sliced scatter

    size_t need = 0;
    auto count = [&](size_t bytes) { need += (bytes + 255) & ~(size_t)255; };
    count((size_t)E * 64 * 2);
    count((size_t)N * 64 * 4);
    count((size_t)N * 64 * 4);
    count((size_t)N * 128 * 4);
    count((size_t)E * 8);                 // spe packed
    count((size_t)(N + 1) * 4);
    count((size_t)N * 4);
    count((size_t)N * 4);
    count((size_t)(G + 1) * 4);
    count((size_t)nblk1 * 256 * 4);
    count((size_t)64 * 256 * 4);
    count(128 * 4); count(128 * 4);
    count((size_t)(nchunk + 1) * 4);
    count(4);
    count(1024 * 4);
    count(4096 * 2);
    if (ws_size < need) {
        hipMemsetAsync(d_out, 0, (size_t)out_size * 4, stream);
        return;
    }

    char* ws = (char*)d_ws;
    size_t off = 0;
    auto alloc = [&](size_t bytes) -> void* {
        void* p = ws + off;
        off += (bytes + 255) & ~(size_t)255;
        return p;
    };
    __hip_bfloat16* e_perm = (__hip_bfloat16*)alloc((size_t)E * 64 * 2);
    float* h_cur    = (float*)alloc((size_t)N * 64 * 4);
    float* y_buf    = (float*)alloc((size_t)N * 64 * 4);
    float* h1       = (float*)alloc((size_t)N * 128 * 4);
    int2*  spe      = (int2*)alloc((size_t)E * 8);
    int*   row_ptr  = (int*)alloc((size_t)(N + 1) * 4);
    int*   counts   = (int*)alloc((size_t)N * 4);
    int*   fill     = (int*)alloc((size_t)N * 4);
    int*   gptr     = (int*)alloc((size_t)(G + 1) * 4);
    float* part     = (float*)alloc((size_t)nblk1 * 256 * 4);
    float* part2    = (float*)alloc((size_t)64 * 256 * 4);
    float* bnscale  = (float*)alloc(128 * 4);
    float* bnshift  = (float*)alloc(128 * 4);
    int*   csum     = (int*)alloc((size_t)(nchunk + 1) * 4);
    int*   totalp   = (int*)alloc(4);
    float* W1t      = (float*)alloc(1024 * 4);
    unsigned short* W2tb = (unsigned short*)alloc(4096 * 2);
    (void)n_in;

    hipMemsetAsync(counts, 0, (size_t)N * 4, stream);
    hipMemsetAsync(fill, 0, (size_t)N * 4, stream);

    const int* src = ei;
    const int* dst = ei + E;

    k_hist<<<(E + 255) / 256, 256, 0, stream>>>(dst, counts, E);
    k_scan1<<<nchunk, 1024, 0, stream>>>(counts, row_ptr, csum, N);
    k_scan2<<<1, 64, 0, stream>>>(csum, nchunk, totalp);
    k_scan3<<<(N + 255) / 256, 256, 0, stream>>>(row_ptr, csum, totalp, N);
    k_scatter<<<nchE * 8, 256, 0, stream>>>(src, dst, row_ptr, fill, spe, E, NS);
    k_gptr<<<(N + 256) / 256, 256, 0, stream>>>(batch, gptr, N, G);
    k_wt<<<16, 256, 0, stream>>>(bondW1, bondW2, W1t, W2tb);

    k_atom<<<(N + TM - 1) / TM, 256, 0, stream>>>(x, atomW1, atomb1, atomW2, atomb2, h_cur, N);
    k_bond<<<(E + 127) / 128, 256, 0, stream>>>(ea, spe, W1t, bondb1, W2tb, bondb2, e_perm, E);

    for (int l = 0; l < Lconv; ++l) {
        k_agg<<<(N + 3) / 4, 256, 0, stream>>>(h_cur, e_perm, spe, row_ptr, convT, l, y_buf, N);
        k_gemm1<<<nblk1, 256, 0, stream>>>(y_buf, convW1 + (size_t)l * 64 * 128,
                                           convb1 + (size_t)l * 128, h1, part, N);
        k_bnred<<<64, 256, 0, stream>>>(part, part2, nblk1);
        k_bnfin<<<1, 1024, 0, stream>>>(part2, convG + (size_t)l * 128, convBt + (size_t)l * 128,
                                        bnscale, bnshift, 1.0f / (float)N);
        k_gemm2<<<(N + 31) / 32, 256, 0, stream>>>(h1, bnscale, bnshift,
                                                   convW2 + (size_t)l * 128 * 64,
                                                   convb2 + (size_t)l * 64, h_cur, N,
                                                   (l < Lconv - 1) ? 1 : 0);
    }

    k_head<<<G, 64, 0, stream>>>(h_cur, gptr, lin1W, lin1b, lin2W, lin2b, out);
}